// Round 16
// baseline (612.242 us; speedup 1.0000x reference)
//
#include <hip/hip_runtime.h>
#include <hip/hip_bf16.h>
#include <cstdint>
#include <cstddef>

#define D_MODEL 4096
#define D_LATENT 512
#define NUM_HEADS 32
#define HEAD_DIM 128
#define BATCH 2
#define SEQ 2048
#define ROWS (BATCH*SEQ)   // 4096

typedef __attribute__((ext_vector_type(8))) short bf16x8;
typedef __attribute__((ext_vector_type(4))) float f32x4;
typedef __attribute__((ext_vector_type(16))) float f32x16;
typedef unsigned int uint;

static __device__ __forceinline__ unsigned short f2bf(float f){
  union { float f; uint32_t u; } v; v.f = f;
  uint32_t r = (v.u + 0x7fffu + ((v.u >> 16) & 1u)) >> 16;
  return (unsigned short)r;
}
static __device__ __forceinline__ float bf2f(unsigned short h){
  union { uint32_t u; float f; } v; v.u = ((uint32_t)h) << 16;
  return v.f;
}
static __device__ __forceinline__ uint cvtpk(float lo, float hi2){
  uint r;
  asm("v_cvt_pk_bf16_f32 %0, %1, %2" : "=v"(r) : "v"(lo), "v"(hi2));
  return r;
}
static __device__ __forceinline__ void gload16(const void* g, void* l){
  __builtin_amdgcn_global_load_lds(
      (const __attribute__((address_space(1))) void*)g,
      (__attribute__((address_space(3))) void*)l, 16, 0, 0);
}

// ---------------------------------------------------------------------------
// prep: blocks [0,8192) convert hidden f32->bf16 (8 elems/thread);
// blocks [8192,8704) fill RoPE cos/sin tables [SEQ][64].
// ---------------------------------------------------------------------------
__global__ __launch_bounds__(256) void prep_kernel(
    const float* __restrict__ in, unsigned short* __restrict__ out,
    float* __restrict__ ct, float* __restrict__ st){
  const int bid = blockIdx.x;
  if (bid < 8192){
    const size_t i = ((size_t)bid * 256 + threadIdx.x) * 8;
    const float4 lo = *(const float4*)(in + i);
    const float4 hi = *(const float4*)(in + i + 4);
    uint4 d; unsigned short* dp = (unsigned short*)&d;
    dp[0]=f2bf(lo.x); dp[1]=f2bf(lo.y); dp[2]=f2bf(lo.z); dp[3]=f2bf(lo.w);
    dp[4]=f2bf(hi.x); dp[5]=f2bf(hi.y); dp[6]=f2bf(hi.z); dp[7]=f2bf(hi.w);
    *(uint4*)(out + i) = d;
  } else {
    const int i = (bid - 8192) * 256 + threadIdx.x;
    if (i >= SEQ * 64) return;
    const int s = i >> 6, j = i & 63;
    const float inv = powf(10000.0f, -(float)j / 64.0f);
    const double a = (double)s * (double)inv;
    ct[i] = (float)cos(a);
    st[i] = (float)sin(a);
  }
}

// ---------------------------------------------------------------------------
// All weight transposes in one launch. [K][N] f32 -> [N][K] bf16, 64x64
// tiles. Flat block ranges: Wq [0,4096), Wo [4096,8192), Wk [8192,8704),
// Wv [8704,9216), Wc [9216,9728).
// ---------------------------------------------------------------------------
static __device__ __forceinline__ void tr_tile(
    const float* __restrict__ W, unsigned short* __restrict__ Wt,
    int K, int N, int k0, int n0){
  __shared__ float tile[64][65];
  const int t = threadIdx.x;
  #pragma unroll
  for (int j = 0; j < 16; ++j){
    const int idx = t + 256*j;
    const int r = idx >> 6, c = idx & 63;
    tile[r][c] = W[(size_t)(k0 + r) * N + n0 + c];
  }
  __syncthreads();
  #pragma unroll
  for (int j = 0; j < 16; ++j){
    const int idx = t + 256*j;
    const int r = idx >> 6, c = idx & 63;
    Wt[(size_t)(n0 + r) * K + k0 + c] = f2bf(tile[c][r]);
  }
}

__global__ __launch_bounds__(256) void transpose_all(
    const float* __restrict__ Wq, unsigned short* __restrict__ Wqt,
    const float* __restrict__ Wo, unsigned short* __restrict__ Wot,
    const float* __restrict__ Wk, unsigned short* __restrict__ Wkt,
    const float* __restrict__ Wv, unsigned short* __restrict__ Wvt,
    const float* __restrict__ Wc, unsigned short* __restrict__ Wct){
  const int b = blockIdx.x;
  if (b < 4096){                       // Wq: K=4096, N=4096
    tr_tile(Wq, Wqt, D_MODEL, D_MODEL, (b & 63) * 64, (b >> 6) * 64);
  } else if (b < 8192){                // Wo
    const int l = b - 4096;
    tr_tile(Wo, Wot, D_MODEL, D_MODEL, (l & 63) * 64, (l >> 6) * 64);
  } else if (b < 8704){                // Wk: K=512, N=4096
    const int l = b - 8192;
    tr_tile(Wk, Wkt, D_LATENT, D_MODEL, (l & 7) * 64, (l >> 3) * 64);
  } else if (b < 9216){                // Wv
    const int l = b - 8704;
    tr_tile(Wv, Wvt, D_LATENT, D_MODEL, (l & 7) * 64, (l >> 3) * 64);
  } else {                             // Wc: K=4096, N=512
    const int l = b - 9216;
    tr_tile(Wc, Wct, D_MODEL, D_LATENT, (l & 63) * 64, (l >> 6) * 64);
  }
}

// ---------------------------------------------------------------------------
// In-place RoPE on bf16 buffer [ROWS][D_MODEL] viewed as [ROWS][H][128].
// ---------------------------------------------------------------------------
__global__ __launch_bounds__(256) void rope_apply(unsigned short* __restrict__ buf,
    const float* __restrict__ ct, const float* __restrict__ st, float scale){
  const int i = blockIdx.x * 256 + threadIdx.x;
  const int j = i & 63;
  const int tmp = i >> 6;
  const int h = tmp & 31;
  const int row = tmp >> 5;
  const int s = row & (SEQ - 1);
  const float c = ct[s*64 + j], sn = st[s*64 + j];
  const size_t base = (size_t)row * D_MODEL + (size_t)h * 128;
  const float x1 = bf2f(buf[base + j]);
  const float x2 = bf2f(buf[base + j + 64]);
  buf[base + j]      = f2bf((x1 * c - x2 * sn) * scale);
  buf[base + j + 64] = f2bf((x2 * c + x1 * sn) * scale);
}

// ---------------------------------------------------------------------------
// 128x128 m97-structure GEMM, generalized output mode:
//   OMODE 0: bf16 C[M][N]
//   OMODE 1: f32 split-K partials Cpart[blockIdx.z][M][N]
//   OMODE 2: Vt transposed scatter -> vt[(b*32+h)*128+d][s]
// XCD-swizzled grid (per z-slice). Kpart==Kfull unless OMODE==1.
// ---------------------------------------------------------------------------
template<int OMODE>
__global__ __launch_bounds__(256) void gemm128_kernel(
    const unsigned short* __restrict__ A, const unsigned short* __restrict__ Bt,
    void* __restrict__ outp, int M, int N, int Kfull, int Kpart){
  __shared__ __align__(16) char As[128 * 128];
  __shared__ __align__(16) char Bs[128 * 128];
  const int t = threadIdx.x;
  const int kz = (OMODE == 1) ? blockIdx.z : 0;
  const int nbx = gridDim.x;
  const int nwg = nbx * gridDim.y;
  int bid = blockIdx.y * nbx + blockIdx.x;
  bid = (bid & 7) * (nwg >> 3) + (bid >> 3);
  const int m0 = (bid / nbx) * 128, n0 = (bid % nbx) * 128;
  const int l = t & 63, wid = t >> 6;
  const int wr = wid >> 1, wcn = wid & 1;
  const int lr = l & 15, lg = l >> 4;

  const int srow = l >> 3;
  const int gch  = (l & 7) ^ srow;
  const size_t kofs = (size_t)kz * Kpart;
  const unsigned short* gA = A  + (size_t)(m0 + wid*32 + srow) * Kfull + kofs + gch*8;
  const unsigned short* gB = Bt + (size_t)(n0 + wid*32 + srow) * Kfull + kofs + gch*8;
  char* lA = As + wid*4096;
  char* lB = Bs + wid*4096;

  f32x4 acc[4][4];
  #pragma unroll
  for (int i = 0; i < 4; ++i)
    #pragma unroll
    for (int j = 0; j < 4; ++j)
      #pragma unroll
      for (int r = 0; r < 4; ++r) acc[i][j][r] = 0.0f;

  const int kTiles = Kpart >> 6;
  for (int kt = 0; kt < kTiles; ++kt){
    const size_t ko = (size_t)kt << 6;
    #pragma unroll
    for (int i = 0; i < 4; ++i){
      gload16(gA + (size_t)i*8*Kfull + ko, lA + i*1024);
      gload16(gB + (size_t)i*8*Kfull + ko, lB + i*1024);
    }
    __syncthreads();
    #pragma unroll
    for (int kc = 0; kc < 2; ++kc){
      bf16x8 af[4], bfv[4];
      const int ch = kc*4 + lg;
      #pragma unroll
      for (int mb = 0; mb < 4; ++mb){
        const int row = wr*64 + mb*16 + lr;
        af[mb] = *(const bf16x8*)(As + row*128 + ((ch ^ (row & 7)) * 16));
      }
      #pragma unroll
      for (int nb = 0; nb < 4; ++nb){
        const int row = wcn*64 + nb*16 + lr;
        bfv[nb] = *(const bf16x8*)(Bs + row*128 + ((ch ^ (row & 7)) * 16));
      }
      #pragma unroll
      for (int mb = 0; mb < 4; ++mb)
        #pragma unroll
        for (int nb = 0; nb < 4; ++nb)
          acc[mb][nb] = __builtin_amdgcn_mfma_f32_16x16x32_bf16(af[mb], bfv[nb], acc[mb][nb], 0, 0, 0);
    }
    __syncthreads();
  }
  #pragma unroll
  for (int mb = 0; mb < 4; ++mb)
    #pragma unroll
    for (int nb = 0; nb < 4; ++nb)
      #pragma unroll
      for (int r = 0; r < 4; ++r){
        const int row = m0 + wr*64 + mb*16 + lg*4 + r;
        const int col = n0 + wcn*64 + nb*16 + lr;
        if constexpr (OMODE == 0){
          ((unsigned short*)outp)[(size_t)row * N + col] = f2bf(acc[mb][nb][r]);
        } else if constexpr (OMODE == 1){
          ((float*)outp)[(size_t)kz * M * N + (size_t)row * N + col] = acc[mb][nb][r];
        } else {
          const size_t didx = ((size_t)(((row >> 11) << 5) | (col >> 7)) * 128
                               + (col & 127)) * SEQ + (row & (SEQ - 1));
          ((unsigned short*)outp)[didx] = f2bf(acc[mb][nb][r]);
        }
      }
}

// ---------------------------------------------------------------------------
// latent partial reduce: bf16 out = f2bf(p0 + p1), 8 elems/thread.
// ---------------------------------------------------------------------------
__global__ __launch_bounds__(256) void latent_reduce(
    const float* __restrict__ p, unsigned short* __restrict__ out, size_t n){
  const size_t i = ((size_t)blockIdx.x * 256 + threadIdx.x) * 8;
  const float4 a0 = *(const float4*)(p + i);
  const float4 a1 = *(const float4*)(p + i + 4);
  const float4 b0 = *(const float4*)(p + n + i);
  const float4 b1 = *(const float4*)(p + n + i + 4);
  uint4 d; unsigned short* dp = (unsigned short*)&d;
  dp[0]=f2bf(a0.x+b0.x); dp[1]=f2bf(a0.y+b0.y); dp[2]=f2bf(a0.z+b0.z); dp[3]=f2bf(a0.w+b0.w);
  dp[4]=f2bf(a1.x+b1.x); dp[5]=f2bf(a1.y+b1.y); dp[6]=f2bf(a1.z+b1.z); dp[7]=f2bf(a1.w+b1.w);
  *(uint4*)(out + i) = d;
}

// ---------------------------------------------------------------------------
// 256x256 8-phase GEMM (T2+T3+T4+T5) + T1 XCD swizzle. Used for the two
// large square GEMMs (Q-proj, O-proj) where K=4096 amortizes the pipeline.
// ---------------------------------------------------------------------------
template<int MH>
static __device__ __forceinline__ void rdAh(bf16x8 (&a_)[4][2], const char* buf,
                                            int wr, int lr, int lg){
  #pragma unroll
  for (int mm = 0; mm < 4; ++mm)
    #pragma unroll
    for (int kc = 0; kc < 2; ++kc){
      const int row = wr*128 + (MH*4 + mm)*16 + lr;
      const int ch = kc*4 + lg;
      a_[mm][kc] = *(const bf16x8*)(buf + row*128 + ((ch ^ (row & 7)) * 16));
    }
}
template<int NH>
static __device__ __forceinline__ void rdBh(bf16x8 (&b_)[2][2][2], const char* buf,
                                            int wc, int lr, int lg){
  #pragma unroll
  for (int nn = 0; nn < 2; ++nn)
    #pragma unroll
    for (int kc = 0; kc < 2; ++kc){
      const int row = wc*64 + (NH*2 + nn)*16 + lr;
      const int ch = kc*4 + lg;
      b_[NH][nn][kc] = *(const bf16x8*)(buf + row*128 + ((ch ^ (row & 7)) * 16));
    }
}
template<int MH, int NH>
static __device__ __forceinline__ void mfq(f32x4 (&acc)[8][4],
    const bf16x8 (&a_)[4][2], const bf16x8 (&b_)[2][2][2]){
  __builtin_amdgcn_s_setprio(1);
  #pragma unroll
  for (int kc = 0; kc < 2; ++kc)
    #pragma unroll
    for (int mm = 0; mm < 4; ++mm)
      #pragma unroll
      for (int nn = 0; nn < 2; ++nn)
        acc[MH*4+mm][NH*2+nn] = __builtin_amdgcn_mfma_f32_16x16x32_bf16(
            a_[mm][kc], b_[NH][nn][kc], acc[MH*4+mm][NH*2+nn], 0, 0, 0);
  __builtin_amdgcn_s_setprio(0);
}

#define G256_BAR  __builtin_amdgcn_s_barrier()
#define G256_LGK0 do{ asm volatile("s_waitcnt lgkmcnt(0)" ::: "memory"); \
                      __builtin_amdgcn_sched_barrier(0); }while(0)
#define G256_VM(n) asm volatile("s_waitcnt vmcnt(" #n ")" ::: "memory")

template<bool OF32>
__global__ __launch_bounds__(512, 2) void gemm256_kernel(
    const unsigned short* __restrict__ A, const unsigned short* __restrict__ Bt,
    void* __restrict__ Cp, int ldc, int M, int N, int K){
  __shared__ __align__(16) char lds[131072];
  char* const As0 = lds;
  char* const As1 = lds + 32768;
  char* const Bs0 = lds + 65536;
  char* const Bs1 = lds + 98304;

  const int t = threadIdx.x;
  const int l = t & 63, wid = t >> 6;
  const int wr = wid >> 2, wc = wid & 3;
  const int lr = l & 15, lg = l >> 4;
  const int nbx = gridDim.x;
  const int nwg = nbx * gridDim.y;
  int bid = blockIdx.y * nbx + blockIdx.x;
  bid = (bid & 7) * (nwg >> 3) + (bid >> 3);
  const int m0 = (bid / nbx) * 256, n0 = (bid % nbx) * 256;

  const int srow = t >> 3;
  const int pch = t & 7;
  const int gch = pch ^ (srow & 7);
  const unsigned short* gAb = A  + (size_t)(m0 + srow) * K + gch*8;
  const unsigned short* gBb = Bt + (size_t)(n0 + srow) * K + gch*8;
  const int ldso = srow*128 + pch*16;

  auto stA = [&](char* dst, int half, int kcol){
    const unsigned short* g = gAb + (size_t)half*128*K + kcol;
    gload16(g,                dst + half*16384 + ldso);
    gload16(g + (size_t)64*K, dst + half*16384 + 8192 + ldso);
  };
  auto stB = [&](char* dst, int half, int kcol){
    const unsigned short* g = gBb + (size_t)half*128*K + kcol;
    gload16(g,                dst + half*16384 + ldso);
    gload16(g + (size_t)64*K, dst + half*16384 + 8192 + ldso);
  };

  f32x4 acc[8][4];
  #pragma unroll
  for (int m = 0; m < 8; ++m)
    #pragma unroll
    for (int n = 0; n < 4; ++n)
      #pragma unroll
      for (int r = 0; r < 4; ++r) acc[m][n][r] = 0.0f;
  bf16x8 a_[4][2];
  bf16x8 b_[2][2][2];

  const int niter = K >> 7;
  stA(As0, 0, 0); stA(As0, 1, 0); stB(Bs0, 0, 0); stB(Bs0, 1, 0);
  stA(As1, 0, 64);
  G256_VM(2);
  G256_BAR;
  __builtin_amdgcn_sched_barrier(0);

  for (int j = 0; j < niter; ++j){
    const int k0 = j << 7;
    const bool more = (j + 1 < niter);
    rdAh<0>(a_, As0, wr, lr, lg);
    rdBh<0>(b_, Bs0, wc, lr, lg);
    stA(As1, 1, k0 + 64);
    G256_BAR; G256_LGK0;
    mfq<0,0>(acc, a_, b_);
    G256_BAR;
    rdBh<1>(b_, Bs0, wc, lr, lg);
    stB(Bs1, 0, k0 + 64);
    G256_BAR; G256_LGK0;
    mfq<0,1>(acc, a_, b_);
    G256_BAR;
    rdAh<1>(a_, As0, wr, lr, lg);
    stB(Bs1, 1, k0 + 64);
    G256_BAR; G256_LGK0;
    mfq<1,0>(acc, a_, b_);
    G256_BAR;
    if (more){ stA(As0, 0, k0 + 128); G256_VM(2); }
    else     { G256_VM(0); }
    G256_BAR;
    __builtin_amdgcn_sched_barrier(0);
    mfq<1,1>(acc, a_, b_);
    G256_BAR;
    rdAh<0>(a_, As1, wr, lr, lg);
    rdBh<0>(b_, Bs1, wc, lr, lg);
    if (more) stA(As0, 1, k0 + 128);
    G256_BAR; G256_LGK0;
    mfq<0,0>(acc, a_, b_);
    G256_BAR;
    rdBh<1>(b_, Bs1, wc, lr, lg);
    if (more) stB(Bs0, 0, k0 + 128);
    G256_BAR; G256_LGK0;
    mfq<0,1>(acc, a_, b_);
    G256_BAR;
    rdAh<1>(a_, As1, wr, lr, lg);
    if (more) stB(Bs0, 1, k0 + 128);
    G256_BAR; G256_LGK0;
    mfq<1,0>(acc, a_, b_);
    G256_BAR;
    if (more){ stA(As1, 0, k0 + 192); G256_VM(2); }
    G256_BAR;
    __builtin_amdgcn_sched_barrier(0);
    mfq<1,1>(acc, a_, b_);
    G256_BAR;
  }

  #pragma unroll
  for (int m = 0; m < 8; ++m)
    #pragma unroll
    for (int n = 0; n < 4; ++n)
      #pragma unroll
      for (int r = 0; r < 4; ++r){
        const int row = m0 + wr*128 + m*16 + lg*4 + r;
        const int col = n0 + wc*64 + n*16 + lr;
        if constexpr (OF32) ((float*)Cp)[(size_t)row * ldc + col] = acc[m][n][r];
        else ((unsigned short*)Cp)[(size_t)row * ldc + col] = f2bf(acc[m][n][r]);
      }
}

// ---------------------------------------------------------------------------
// Flash attention, 8 waves x 32 q-rows, KVBLK=64, 32x32x16 MFMA.
// Proven R10 body, byte-identical to R15.
// ---------------------------------------------------------------------------
__global__ __launch_bounds__(512) void attn_kernel(
    const unsigned short* __restrict__ q, const unsigned short* __restrict__ kp,
    const unsigned short* __restrict__ vt, const float* __restrict__ ct,
    const float* __restrict__ st, unsigned short* __restrict__ o){
  __shared__ __align__(16) char Ks[2 * 16384];
  __shared__ __align__(16) char Vs[2 * 16384];
  const int t = threadIdx.x;
  const int l = t & 63, w = t >> 6;
  const int lq = l & 31, hi = l >> 5;
  const int bh = blockIdx.x, qb = blockIdx.y;   // bh-major: qb shares XCD
  const int b = bh >> 5;
  const size_t qbase = (size_t)b * SEQ + qb*256 + w*32;
  const size_t cb = (size_t)(bh & 31) * 128;

  auto stageK = [&](int buf, int kb){
    const size_t kr0 = (size_t)b * SEQ + (size_t)kb*64;
    char* kdst = Ks + buf*16384 + w*2048;
    #pragma unroll
    for (int i = 0; i < 2; ++i){
      const int r = w*8 + i*4 + (l >> 4);
      const int g = (l & 15) ^ (r & 15);
      gload16(kp + (kr0 + r) * D_MODEL + cb + g*8, kdst + i*1024);
    }
  };
  auto stageV = [&](int buf, int kb){
    char* vdst = Vs + buf*16384 + w*2048;
    #pragma unroll
    for (int i = 0; i < 2; ++i){
      const int r = w*16 + i*8 + (l >> 3);
      const int g = (l & 7) ^ (r & 7);
      gload16(vt + ((size_t)bh*128 + r) * SEQ + (size_t)kb*64 + g*8, vdst + i*1024);
    }
  };

  // Q load + in-register RoPE + scale (1/sqrt(Dh) * log2e -> exp2 softmax)
  bf16x8 qf[8];
  #pragma unroll
  for (int dc = 0; dc < 8; ++dc)
    qf[dc] = *(const bf16x8*)(q + (qbase + lq) * D_MODEL + cb + dc*16 + hi*8);
  {
    const float qsc = 0.08838834764831845f * 1.4426950408889634f;
    const int s = qb*256 + w*32 + lq;
    #pragma unroll
    for (int dc = 0; dc < 4; ++dc){
      const int j0 = dc*16 + hi*8;
      const float4 c0 = *(const float4*)(ct + s*64 + j0);
      const float4 c1 = *(const float4*)(ct + s*64 + j0 + 4);
      const float4 s0_ = *(const float4*)(st + s*64 + j0);
      const float4 s1_ = *(const float4*)(st + s*64 + j0 + 4);
      const float cc[8] = {c0.x,c0.y,c0.z,c0.w,c1.x,c1.y,c1.z,c1.w};
      const float ss[8] = {s0_.x,s0_.y,s0_.z,s0_.w,s1_.x,s1_.y,s1_.z,s1_.w};
      #pragma unroll
      for (int e = 0; e < 8; ++e){
        const float x1 = bf2f((unsigned short)qf[dc][e]);
        const float x2 = bf2f((unsigned short)qf[dc + 4][e]);
        qf[dc][e]     = (short)f2bf((x1 * cc[e] - x2 * ss[e]) * qsc);
        qf[dc + 4][e] = (short)f2bf((x2 * cc[e] + x1 * ss[e]) * qsc);
      }
    }
  }

  f32x16 O[4];
  #pragma unroll
  for (int nb = 0; nb < 4; ++nb)
    #pragma unroll
    for (int r = 0; r < 16; ++r) O[nb][r] = 0.0f;
  float m = -1e30f, lsum = 0.0f;

  stageK(0, 0); stageV(0, 0);

  for (int kb = 0; kb < SEQ/64; ++kb){
    const bool more = (kb + 1 < SEQ/64);
    asm volatile("s_waitcnt vmcnt(0)" ::: "memory");
    __builtin_amdgcn_s_barrier();
    __builtin_amdgcn_sched_barrier(0);
    if (more){ stageK((kb + 1) & 1, kb + 1); stageV((kb + 1) & 1, kb + 1); }
    const char* Kb = Ks + (kb & 1)*16384;
    const char* Vb = Vs + (kb & 1)*16384;

    // S^T = K * Q^T (scores in log2 domain)
    f32x16 s0, s1;
    #pragma unroll
    for (int r = 0; r < 16; ++r){ s0[r] = 0.0f; s1[r] = 0.0f; }
    __builtin_amdgcn_s_setprio(1);
    #pragma unroll
    for (int dc = 0; dc < 8; ++dc){
      const int ch = dc*2 + hi;
      const bf16x8 k0 = *(const bf16x8*)(Kb + lq*256 + ((ch ^ (lq & 15)) * 16));
      const bf16x8 k1 = *(const bf16x8*)(Kb + (32 + lq)*256 + ((ch ^ (lq & 15)) * 16));
      s0 = __builtin_amdgcn_mfma_f32_32x32x16_bf16(k0, qf[dc], s0, 0, 0, 0);
      s1 = __builtin_amdgcn_mfma_f32_32x32x16_bf16(k1, qf[dc], s1, 0, 0, 0);
    }
    __builtin_amdgcn_s_setprio(0);

    // online softmax (proven shfl_xor cross-half reductions)
    float mt = s0[0];
    #pragma unroll
    for (int r = 1; r < 16; ++r) mt = fmaxf(mt, s0[r]);
    #pragma unroll
    for (int r = 0; r < 16; ++r) mt = fmaxf(mt, s1[r]);
    mt = fmaxf(mt, __shfl_xor(mt, 32));

    if (!__all(mt <= m + 8.0f)){
      const float mnew = fmaxf(m, mt);
      const float al = __builtin_amdgcn_exp2f(m - mnew);
      m = mnew;
      lsum *= al;
      #pragma unroll
      for (int r = 0; r < 16; ++r){
        const int crow = (r & 3) + 8*(r >> 2) + 4*hi;
        const float albr = __shfl(al, crow);
        #pragma unroll
        for (int nb = 0; nb < 4; ++nb) O[nb][r] *= albr;
      }
    }

    float E[32];
    float sum = 0.0f;
    #pragma unroll
    for (int r = 0; r < 16; ++r){ E[r] = __builtin_amdgcn_exp2f(s0[r] - m); sum += E[r]; }
    #pragma unroll
    for (int r = 0; r < 16; ++r){ E[16 + r] = __builtin_amdgcn_exp2f(s1[r] - m); sum += E[16 + r]; }
    sum += __shfl_xor(sum, 32);
    lsum += sum;

    // repack P (C-layout) -> PV A-fragments (proven R7 shfl_xor + select)
    bf16x8 pa[4];
    #pragma unroll
    for (int c = 0; c < 4; ++c){
      const int rb = c * 8;
      const uint a_ = cvtpk(E[rb + 0], E[rb + 1]);
      const uint b_ = cvtpk(E[rb + 2], E[rb + 3]);
      const uint c_ = cvtpk(E[rb + 4], E[rb + 5]);
      const uint d_ = cvtpk(E[rb + 6], E[rb + 7]);
      const uint sa = (uint)__shfl_xor((int)a_, 32);
      const uint sb = (uint)__shfl_xor((int)b_, 32);
      const uint sc = (uint)__shfl_xor((int)c_, 32);
      const uint sd = (uint)__shfl_xor((int)d_, 32);
      union { uint u[4]; bf16x8 v; } uu;
      uu.u[0] = hi ? sc : a_;
      uu.u[1] = hi ? sd : b_;
      uu.u[2] = hi ? c_ : sa;
      uu.u[3] = hi ? d_ : sb;
      pa[c] = uu.v;
    }

    // O += P * V
    __builtin_amdgcn_s_setprio(1);
    #pragma unroll
    for (int c = 0; c < 4; ++c){
      const int ch = c*2 + hi;
      #pragma unroll
      for (int nb = 0; nb < 4; ++nb){
        const int vr = nb*32 + lq;
        const bf16x8 vf = *(const bf16x8*)(Vb + vr*128 + ((ch ^ (vr & 7)) * 16));
        O[nb] = __builtin_amdgcn_mfma_f32_32x32x16_bf16(pa[c], vf, O[nb], 0, 0, 0);
      }
    }
    __builtin_amdgcn_s_setprio(0);
  }

  const float rinv = 1.0f / lsum;
  #pragma unroll
  for (int r = 0; r < 16; ++r){
    const int crow = (r & 3) + 8*(r >> 2) + 4*hi;
    const float rb_ = __shfl(rinv, crow);
    #pragma unroll
    for (int nb = 0; nb < 4; ++nb)
      o[(qbase + crow) * D_MODEL + cb + nb*32 + lq] = f2bf(O[nb][r] * rb_);
  }
}

// ---------------------------------------------------------------------------
extern "C" void kernel_launch(void* const* d_in, const int* in_sizes, int n_in,
                              void* d_out, int out_size, void* d_ws, size_t ws_size,
                              hipStream_t stream){
  const float* hidden = (const float*)d_in[0];
  const float* Wq = (const float*)d_in[1];
  const float* Wc = (const float*)d_in[2];
  const float* Wk = (const float*)d_in[3];
  const float* Wv = (const float*)d_in[4];
  const float* Wo = (const float*)d_in[5];
  float* out = (float*)d_out;

  char* ws = (char*)d_ws;
  size_t off = 0;
  auto alloc = [&](size_t bytes)->char*{
    char* p = ws + off; off += (bytes + 255) & ~(size_t)255; return p;
  };
  unsigned short* Wqt  = (unsigned short*)alloc((size_t)D_MODEL * D_MODEL * 2);   // 32 MB
  unsigned short* Wct  = (unsigned short*)alloc((size_t)D_LATENT * D_MODEL * 2);  // 4 MB
  unsigned short* Wkvt = (unsigned short*)alloc((size_t)2 * D_MODEL * D_LATENT * 2);
  unsigned short* Wot  = (unsigned short*)alloc((size_t)D_MODEL * D_MODEL * 2);
  unsigned short* latent = (unsigned short*)alloc((size_t)ROWS * D_LATENT * 2);
  unsigned short* qbuf = (unsigned short*)alloc((size_t)ROWS * D_MODEL * 2);
  unsigned short* kbuf = (unsigned short*)alloc((size_t)ROWS * D_MODEL * 2);
  unsigned short* attnb= (unsigned short*)alloc((size_t)ROWS * D_MODEL * 2);
  float* lpart = (float*)alloc((size_t)2 * ROWS * D_LATENT * 4);  // 16 MB
  float* ctab = (float*)alloc((size_t)SEQ * 64 * 4);
  float* stab = (float*)alloc((size_t)SEQ * 64 * 4);
  unsigned short* hbf   = attnb;  // alias: dead until attention writes it
  // Vt [64][128][SEQ] = 33.5MB aliases Wqt (32MB) + first 1.5MB of Wct;
  // both dead by the time the V-proj writes.
  unsigned short* vtbuf = Wqt;

  const dim3 B256(256);

  // merged preprocessing: hidden convert + rope tables; all 5 transposes
  prep_kernel<<<8704, B256, 0, stream>>>(hidden, hbf, ctab, stab);
  transpose_all<<<9728, B256, 0, stream>>>(
      Wq, Wqt, Wo, Wot, Wk, Wkvt, Wv, Wkvt + (size_t)D_MODEL*D_LATENT, Wc, Wct);

  // latent projection: split-K x2 (256 blocks) -> f32 partials -> reduce
  gemm128_kernel<1><<<dim3(D_LATENT/128, ROWS/128, 2), B256, 0, stream>>>(
      hbf, Wct, lpart, ROWS, D_LATENT, D_MODEL, D_MODEL/2);
  latent_reduce<<<(ROWS*(size_t)D_LATENT)/2048, B256, 0, stream>>>(
      lpart, latent, (size_t)ROWS * D_LATENT);

  // Q projection (256x256 8-phase, K=4096)
  gemm256_kernel<false><<<dim3(D_MODEL/256, ROWS/256), dim3(512), 0, stream>>>(
      hbf, Wqt, qbuf, D_MODEL, ROWS, D_MODEL, D_MODEL);

  // K and V projections: 128-tile structure (K=512 is fill-dominated on the
  // 8-phase template; m97 structure measured ~905 TF at this shape).
  gemm128_kernel<0><<<dim3(D_MODEL/128, ROWS/128), B256, 0, stream>>>(
      latent, Wkvt, kbuf, ROWS, D_MODEL, D_LATENT, D_LATENT);
  gemm128_kernel<2><<<dim3(D_MODEL/128, ROWS/128), B256, 0, stream>>>(
      latent, Wkvt + (size_t)D_MODEL*D_LATENT, vtbuf, ROWS, D_MODEL, D_LATENT, D_LATENT);

  // RoPE on K only (Q-RoPE folded into attn)
  rope_apply<<<(ROWS * NUM_HEADS * 64) / 256, B256, 0, stream>>>(kbuf, ctab, stab, 1.0f);

  // attention
  attn_kernel<<<dim3(BATCH * NUM_HEADS, SEQ/256), dim3(512), 0, stream>>>(
      qbuf, kbuf, vtbuf, ctab, stab, attnb);

  // output projection (f32 out)
  gemm256_kernel<true><<<dim3(D_MODEL/256, ROWS/256), dim3(512), 0, stream>>>(
      attnb, Wot, out, D_MODEL, ROWS, D_MODEL, D_MODEL);
}

// Round 17
// 577.825 us; speedup vs baseline: 1.0596x; 1.0596x over previous
//
#include <hip/hip_runtime.h>
#include <hip/hip_bf16.h>
#include <cstdint>
#include <cstddef>

#define D_MODEL 4096
#define D_LATENT 512
#define NUM_HEADS 32
#define HEAD_DIM 128
#define BATCH 2
#define SEQ 2048
#define ROWS (BATCH*SEQ)   // 4096

typedef __attribute__((ext_vector_type(8))) short bf16x8;
typedef __attribute__((ext_vector_type(4))) float f32x4;
typedef __attribute__((ext_vector_type(16))) float f32x16;
typedef unsigned int uint;

static __device__ __forceinline__ unsigned short f2bf(float f){
  union { float f; uint32_t u; } v; v.f = f;
  uint32_t r = (v.u + 0x7fffu + ((v.u >> 16) & 1u)) >> 16;
  return (unsigned short)r;
}
static __device__ __forceinline__ float bf2f(unsigned short h){
  union { uint32_t u; float f; } v; v.u = ((uint32_t)h) << 16;
  return v.f;
}
static __device__ __forceinline__ uint cvtpk(float lo, float hi2){
  uint r;
  asm("v_cvt_pk_bf16_f32 %0, %1, %2" : "=v"(r) : "v"(lo), "v"(hi2));
  return r;
}
static __device__ __forceinline__ void gload16(const void* g, void* l){
  __builtin_amdgcn_global_load_lds(
      (const __attribute__((address_space(1))) void*)g,
      (__attribute__((address_space(3))) void*)l, 16, 0, 0);
}

// ---------------------------------------------------------------------------
// prep: blocks [0,8192) convert hidden f32->bf16 (8 elems/thread);
// blocks [8192,8704) fill RoPE cos/sin tables [SEQ][64].
// ---------------------------------------------------------------------------
__global__ __launch_bounds__(256) void prep_kernel(
    const float* __restrict__ in, unsigned short* __restrict__ out,
    float* __restrict__ ct, float* __restrict__ st){
  const int bid = blockIdx.x;
  if (bid < 8192){
    const size_t i = ((size_t)bid * 256 + threadIdx.x) * 8;
    const float4 lo = *(const float4*)(in + i);
    const float4 hi = *(const float4*)(in + i + 4);
    uint4 d; unsigned short* dp = (unsigned short*)&d;
    dp[0]=f2bf(lo.x); dp[1]=f2bf(lo.y); dp[2]=f2bf(lo.z); dp[3]=f2bf(lo.w);
    dp[4]=f2bf(hi.x); dp[5]=f2bf(hi.y); dp[6]=f2bf(hi.z); dp[7]=f2bf(hi.w);
    *(uint4*)(out + i) = d;
  } else {
    const int i = (bid - 8192) * 256 + threadIdx.x;
    if (i >= SEQ * 64) return;
    const int s = i >> 6, j = i & 63;
    const float inv = powf(10000.0f, -(float)j / 64.0f);
    const double a = (double)s * (double)inv;
    ct[i] = (float)cos(a);
    st[i] = (float)sin(a);
  }
}

// ---------------------------------------------------------------------------
// All weight transposes in one launch. [K][N] f32 -> [N][K] bf16, 64x64
// tiles. Flat block ranges: Wq [0,4096), Wo [4096,8192), Wk [8192,8704),
// Wv [8704,9216), Wc [9216,9728).
// ---------------------------------------------------------------------------
static __device__ __forceinline__ void tr_tile(
    const float* __restrict__ W, unsigned short* __restrict__ Wt,
    int K, int N, int k0, int n0){
  __shared__ float tile[64][65];
  const int t = threadIdx.x;
  #pragma unroll
  for (int j = 0; j < 16; ++j){
    const int idx = t + 256*j;
    const int r = idx >> 6, c = idx & 63;
    tile[r][c] = W[(size_t)(k0 + r) * N + n0 + c];
  }
  __syncthreads();
  #pragma unroll
  for (int j = 0; j < 16; ++j){
    const int idx = t + 256*j;
    const int r = idx >> 6, c = idx & 63;
    Wt[(size_t)(n0 + r) * K + k0 + c] = f2bf(tile[c][r]);
  }
}

__global__ __launch_bounds__(256) void transpose_all(
    const float* __restrict__ Wq, unsigned short* __restrict__ Wqt,
    const float* __restrict__ Wo, unsigned short* __restrict__ Wot,
    const float* __restrict__ Wk, unsigned short* __restrict__ Wkt,
    const float* __restrict__ Wv, unsigned short* __restrict__ Wvt,
    const float* __restrict__ Wc, unsigned short* __restrict__ Wct){
  const int b = blockIdx.x;
  if (b < 4096){                       // Wq: K=4096, N=4096
    tr_tile(Wq, Wqt, D_MODEL, D_MODEL, (b & 63) * 64, (b >> 6) * 64);
  } else if (b < 8192){                // Wo
    const int l = b - 4096;
    tr_tile(Wo, Wot, D_MODEL, D_MODEL, (l & 63) * 64, (l >> 6) * 64);
  } else if (b < 8704){                // Wk: K=512, N=4096
    const int l = b - 8192;
    tr_tile(Wk, Wkt, D_LATENT, D_MODEL, (l & 7) * 64, (l >> 3) * 64);
  } else if (b < 9216){                // Wv
    const int l = b - 8704;
    tr_tile(Wv, Wvt, D_LATENT, D_MODEL, (l & 7) * 64, (l >> 3) * 64);
  } else {                             // Wc: K=4096, N=512
    const int l = b - 9216;
    tr_tile(Wc, Wct, D_MODEL, D_LATENT, (l & 63) * 64, (l >> 6) * 64);
  }
}

// ---------------------------------------------------------------------------
// In-place RoPE on bf16 buffer [ROWS][D_MODEL] viewed as [ROWS][H][128].
// ---------------------------------------------------------------------------
__global__ __launch_bounds__(256) void rope_apply(unsigned short* __restrict__ buf,
    const float* __restrict__ ct, const float* __restrict__ st, float scale){
  const int i = blockIdx.x * 256 + threadIdx.x;
  const int j = i & 63;
  const int tmp = i >> 6;
  const int h = tmp & 31;
  const int row = tmp >> 5;
  const int s = row & (SEQ - 1);
  const float c = ct[s*64 + j], sn = st[s*64 + j];
  const size_t base = (size_t)row * D_MODEL + (size_t)h * 128;
  const float x1 = bf2f(buf[base + j]);
  const float x2 = bf2f(buf[base + j + 64]);
  buf[base + j]      = f2bf((x1 * c - x2 * sn) * scale);
  buf[base + j + 64] = f2bf((x2 * c + x1 * sn) * scale);
}

// ---------------------------------------------------------------------------
// 128x128 split-K GEMM for the latent projection: blockIdx.z = K-half,
// writes f32 partials to Cpart[z]. XCD-swizzled grid (per z-slice).
// ---------------------------------------------------------------------------
__global__ __launch_bounds__(256) void gemm_splitk_kernel(
    const unsigned short* __restrict__ A, const unsigned short* __restrict__ Bt,
    float* __restrict__ Cpart, int M, int N, int Kfull, int Kpart){
  __shared__ __align__(16) char As[128 * 128];
  __shared__ __align__(16) char Bs[128 * 128];
  const int t = threadIdx.x;
  const int kz = blockIdx.z;
  const int nbx = gridDim.x;
  const int nwg = nbx * gridDim.y;
  int bid = blockIdx.y * nbx + blockIdx.x;
  bid = (bid & 7) * (nwg >> 3) + (bid >> 3);
  const int m0 = (bid / nbx) * 128, n0 = (bid % nbx) * 128;
  const int l = t & 63, wid = t >> 6;
  const int wr = wid >> 1, wcn = wid & 1;
  const int lr = l & 15, lg = l >> 4;

  const int srow = l >> 3;
  const int gch  = (l & 7) ^ srow;
  const size_t kofs = (size_t)kz * Kpart;
  const unsigned short* gA = A  + (size_t)(m0 + wid*32 + srow) * Kfull + kofs + gch*8;
  const unsigned short* gB = Bt + (size_t)(n0 + wid*32 + srow) * Kfull + kofs + gch*8;
  char* lA = As + wid*4096;
  char* lB = Bs + wid*4096;

  f32x4 acc[4][4];
  #pragma unroll
  for (int i = 0; i < 4; ++i)
    #pragma unroll
    for (int j = 0; j < 4; ++j)
      #pragma unroll
      for (int r = 0; r < 4; ++r) acc[i][j][r] = 0.0f;

  const int kTiles = Kpart >> 6;
  for (int kt = 0; kt < kTiles; ++kt){
    const size_t ko = (size_t)kt << 6;
    #pragma unroll
    for (int i = 0; i < 4; ++i){
      gload16(gA + (size_t)i*8*Kfull + ko, lA + i*1024);
      gload16(gB + (size_t)i*8*Kfull + ko, lB + i*1024);
    }
    __syncthreads();
    #pragma unroll
    for (int kc = 0; kc < 2; ++kc){
      bf16x8 af[4], bfv[4];
      const int ch = kc*4 + lg;
      #pragma unroll
      for (int mb = 0; mb < 4; ++mb){
        const int row = wr*64 + mb*16 + lr;
        af[mb] = *(const bf16x8*)(As + row*128 + ((ch ^ (row & 7)) * 16));
      }
      #pragma unroll
      for (int nb = 0; nb < 4; ++nb){
        const int row = wcn*64 + nb*16 + lr;
        bfv[nb] = *(const bf16x8*)(Bs + row*128 + ((ch ^ (row & 7)) * 16));
      }
      #pragma unroll
      for (int mb = 0; mb < 4; ++mb)
        #pragma unroll
        for (int nb = 0; nb < 4; ++nb)
          acc[mb][nb] = __builtin_amdgcn_mfma_f32_16x16x32_bf16(af[mb], bfv[nb], acc[mb][nb], 0, 0, 0);
    }
    __syncthreads();
  }
  float* Cp = Cpart + (size_t)kz * M * N;
  #pragma unroll
  for (int mb = 0; mb < 4; ++mb)
    #pragma unroll
    for (int nb = 0; nb < 4; ++nb)
      #pragma unroll
      for (int r = 0; r < 4; ++r){
        const int row = m0 + wr*64 + mb*16 + lg*4 + r;
        const int col = n0 + wcn*64 + nb*16 + lr;
        Cp[(size_t)row * N + col] = acc[mb][nb][r];
      }
}

// ---------------------------------------------------------------------------
// latent partial reduce: bf16 out = f2bf(p0 + p1), 8 elems/thread.
// ---------------------------------------------------------------------------
__global__ __launch_bounds__(256) void latent_reduce(
    const float* __restrict__ p, unsigned short* __restrict__ out, size_t n){
  const size_t i = ((size_t)blockIdx.x * 256 + threadIdx.x) * 8;
  const float4 a0 = *(const float4*)(p + i);
  const float4 a1 = *(const float4*)(p + i + 4);
  const float4 b0 = *(const float4*)(p + n + i);
  const float4 b1 = *(const float4*)(p + n + i + 4);
  uint4 d; unsigned short* dp = (unsigned short*)&d;
  dp[0]=f2bf(a0.x+b0.x); dp[1]=f2bf(a0.y+b0.y); dp[2]=f2bf(a0.z+b0.z); dp[3]=f2bf(a0.w+b0.w);
  dp[4]=f2bf(a1.x+b1.x); dp[5]=f2bf(a1.y+b1.y); dp[6]=f2bf(a1.z+b1.z); dp[7]=f2bf(a1.w+b1.w);
  *(uint4*)(out + i) = d;
}

// ---------------------------------------------------------------------------
// 256x256 8-phase GEMM (T2+T3+T4+T5) + T1 XCD swizzle. Split-output
// epilogue: cols >= nsplit go to Cp2 (ldc2). vt_mode=1: Cp2 is Vt
// [B*H][128][SEQ], V half scatter-written transposed.
// ---------------------------------------------------------------------------
template<int MH>
static __device__ __forceinline__ void rdAh(bf16x8 (&a_)[4][2], const char* buf,
                                            int wr, int lr, int lg){
  #pragma unroll
  for (int mm = 0; mm < 4; ++mm)
    #pragma unroll
    for (int kc = 0; kc < 2; ++kc){
      const int row = wr*128 + (MH*4 + mm)*16 + lr;
      const int ch = kc*4 + lg;
      a_[mm][kc] = *(const bf16x8*)(buf + row*128 + ((ch ^ (row & 7)) * 16));
    }
}
template<int NH>
static __device__ __forceinline__ void rdBh(bf16x8 (&b_)[2][2][2], const char* buf,
                                            int wc, int lr, int lg){
  #pragma unroll
  for (int nn = 0; nn < 2; ++nn)
    #pragma unroll
    for (int kc = 0; kc < 2; ++kc){
      const int row = wc*64 + (NH*2 + nn)*16 + lr;
      const int ch = kc*4 + lg;
      b_[NH][nn][kc] = *(const bf16x8*)(buf + row*128 + ((ch ^ (row & 7)) * 16));
    }
}
template<int MH, int NH>
static __device__ __forceinline__ void mfq(f32x4 (&acc)[8][4],
    const bf16x8 (&a_)[4][2], const bf16x8 (&b_)[2][2][2]){
  __builtin_amdgcn_s_setprio(1);
  #pragma unroll
  for (int kc = 0; kc < 2; ++kc)
    #pragma unroll
    for (int mm = 0; mm < 4; ++mm)
      #pragma unroll
      for (int nn = 0; nn < 2; ++nn)
        acc[MH*4+mm][NH*2+nn] = __builtin_amdgcn_mfma_f32_16x16x32_bf16(
            a_[mm][kc], b_[NH][nn][kc], acc[MH*4+mm][NH*2+nn], 0, 0, 0);
  __builtin_amdgcn_s_setprio(0);
}

#define G256_BAR  __builtin_amdgcn_s_barrier()
#define G256_LGK0 do{ asm volatile("s_waitcnt lgkmcnt(0)" ::: "memory"); \
                      __builtin_amdgcn_sched_barrier(0); }while(0)
#define G256_VM(n) asm volatile("s_waitcnt vmcnt(" #n ")" ::: "memory")

template<bool OF32>
__global__ __launch_bounds__(512, 2) void gemm256_kernel(
    const unsigned short* __restrict__ A, const unsigned short* __restrict__ Bt,
    void* __restrict__ Cp, void* __restrict__ Cp2, int nsplit, int ldc, int ldc2,
    int M, int N, int K, int vt_mode){
  __shared__ __align__(16) char lds[131072];
  char* const As0 = lds;
  char* const As1 = lds + 32768;
  char* const Bs0 = lds + 65536;
  char* const Bs1 = lds + 98304;

  const int t = threadIdx.x;
  const int l = t & 63, wid = t >> 6;
  const int wr = wid >> 2, wc = wid & 3;
  const int lr = l & 15, lg = l >> 4;
  const int nbx = gridDim.x;
  const int nwg = nbx * gridDim.y;
  int bid = blockIdx.y * nbx + blockIdx.x;
  bid = (bid & 7) * (nwg >> 3) + (bid >> 3);
  const int m0 = (bid / nbx) * 256, n0 = (bid % nbx) * 256;

  const int srow = t >> 3;
  const int pch = t & 7;
  const int gch = pch ^ (srow & 7);
  const unsigned short* gAb = A  + (size_t)(m0 + srow) * K + gch*8;
  const unsigned short* gBb = Bt + (size_t)(n0 + srow) * K + gch*8;
  const int ldso = srow*128 + pch*16;

  auto stA = [&](char* dst, int half, int kcol){
    const unsigned short* g = gAb + (size_t)half*128*K + kcol;
    gload16(g,                dst + half*16384 + ldso);
    gload16(g + (size_t)64*K, dst + half*16384 + 8192 + ldso);
  };
  auto stB = [&](char* dst, int half, int kcol){
    const unsigned short* g = gBb + (size_t)half*128*K + kcol;
    gload16(g,                dst + half*16384 + ldso);
    gload16(g + (size_t)64*K, dst + half*16384 + 8192 + ldso);
  };

  f32x4 acc[8][4];
  #pragma unroll
  for (int m = 0; m < 8; ++m)
    #pragma unroll
    for (int n = 0; n < 4; ++n)
      #pragma unroll
      for (int r = 0; r < 4; ++r) acc[m][n][r] = 0.0f;
  bf16x8 a_[4][2];
  bf16x8 b_[2][2][2];

  const int niter = K >> 7;
  stA(As0, 0, 0); stA(As0, 1, 0); stB(Bs0, 0, 0); stB(Bs0, 1, 0);
  stA(As1, 0, 64);
  G256_VM(2);
  G256_BAR;
  __builtin_amdgcn_sched_barrier(0);

  for (int j = 0; j < niter; ++j){
    const int k0 = j << 7;
    const bool more = (j + 1 < niter);
    rdAh<0>(a_, As0, wr, lr, lg);
    rdBh<0>(b_, Bs0, wc, lr, lg);
    stA(As1, 1, k0 + 64);
    G256_BAR; G256_LGK0;
    mfq<0,0>(acc, a_, b_);
    G256_BAR;
    rdBh<1>(b_, Bs0, wc, lr, lg);
    stB(Bs1, 0, k0 + 64);
    G256_BAR; G256_LGK0;
    mfq<0,1>(acc, a_, b_);
    G256_BAR;
    rdAh<1>(a_, As0, wr, lr, lg);
    stB(Bs1, 1, k0 + 64);
    G256_BAR; G256_LGK0;
    mfq<1,0>(acc, a_, b_);
    G256_BAR;
    if (more){ stA(As0, 0, k0 + 128); G256_VM(2); }
    else     { G256_VM(0); }
    G256_BAR;
    __builtin_amdgcn_sched_barrier(0);
    mfq<1,1>(acc, a_, b_);
    G256_BAR;
    rdAh<0>(a_, As1, wr, lr, lg);
    rdBh<0>(b_, Bs1, wc, lr, lg);
    if (more) stA(As0, 1, k0 + 128);
    G256_BAR; G256_LGK0;
    mfq<0,0>(acc, a_, b_);
    G256_BAR;
    rdBh<1>(b_, Bs1, wc, lr, lg);
    if (more) stB(Bs0, 0, k0 + 128);
    G256_BAR; G256_LGK0;
    mfq<0,1>(acc, a_, b_);
    G256_BAR;
    rdAh<1>(a_, As1, wr, lr, lg);
    if (more) stB(Bs0, 1, k0 + 128);
    G256_BAR; G256_LGK0;
    mfq<1,0>(acc, a_, b_);
    G256_BAR;
    if (more){ stA(As1, 0, k0 + 192); G256_VM(2); }
    G256_BAR;
    __builtin_amdgcn_sched_barrier(0);
    mfq<1,1>(acc, a_, b_);
    G256_BAR;
  }

  if (n0 >= nsplit && vt_mode){
    unsigned short* vtp = (unsigned short*)Cp2;
    #pragma unroll
    for (int m = 0; m < 8; ++m)
      #pragma unroll
      for (int n = 0; n < 4; ++n)
        #pragma unroll
        for (int r = 0; r < 4; ++r){
          const int row = m0 + wr*128 + m*16 + lg*4 + r;   // b*SEQ + s
          const int col = (n0 - nsplit) + wc*64 + n*16 + lr; // h*128 + d
          const size_t didx = ((size_t)(((row >> 11) << 5) | (col >> 7)) * 128
                               + (col & 127)) * SEQ + (row & (SEQ - 1));
          vtp[didx] = f2bf(acc[m][n][r]);
        }
    return;
  }
  void* outp = Cp;
  int c0 = n0, ld = ldc;
  if (n0 >= nsplit){ outp = Cp2; c0 = n0 - nsplit; ld = ldc2; }
  #pragma unroll
  for (int m = 0; m < 8; ++m)
    #pragma unroll
    for (int n = 0; n < 4; ++n)
      #pragma unroll
      for (int r = 0; r < 4; ++r){
        const int row = m0 + wr*128 + m*16 + lg*4 + r;
        const int col = c0 + wc*64 + n*16 + lr;
        if constexpr (OF32) ((float*)outp)[(size_t)row * ld + col] = acc[m][n][r];
        else ((unsigned short*)outp)[(size_t)row * ld + col] = f2bf(acc[m][n][r]);
      }
}

// ---------------------------------------------------------------------------
// Flash attention, 8 waves x 32 q-rows, KVBLK=64, 32x32x16 MFMA.
// Proven R10 body, byte-identical to R15.
// ---------------------------------------------------------------------------
__global__ __launch_bounds__(512) void attn_kernel(
    const unsigned short* __restrict__ q, const unsigned short* __restrict__ kp,
    const unsigned short* __restrict__ vt, const float* __restrict__ ct,
    const float* __restrict__ st, unsigned short* __restrict__ o){
  __shared__ __align__(16) char Ks[2 * 16384];
  __shared__ __align__(16) char Vs[2 * 16384];
  const int t = threadIdx.x;
  const int l = t & 63, w = t >> 6;
  const int lq = l & 31, hi = l >> 5;
  const int bh = blockIdx.x, qb = blockIdx.y;   // bh-major: qb shares XCD
  const int b = bh >> 5;
  const size_t qbase = (size_t)b * SEQ + qb*256 + w*32;
  const size_t cb = (size_t)(bh & 31) * 128;

  auto stageK = [&](int buf, int kb){
    const size_t kr0 = (size_t)b * SEQ + (size_t)kb*64;
    char* kdst = Ks + buf*16384 + w*2048;
    #pragma unroll
    for (int i = 0; i < 2; ++i){
      const int r = w*8 + i*4 + (l >> 4);
      const int g = (l & 15) ^ (r & 15);
      gload16(kp + (kr0 + r) * D_MODEL + cb + g*8, kdst + i*1024);
    }
  };
  auto stageV = [&](int buf, int kb){
    char* vdst = Vs + buf*16384 + w*2048;
    #pragma unroll
    for (int i = 0; i < 2; ++i){
      const int r = w*16 + i*8 + (l >> 3);
      const int g = (l & 7) ^ (r & 7);
      gload16(vt + ((size_t)bh*128 + r) * SEQ + (size_t)kb*64 + g*8, vdst + i*1024);
    }
  };

  // Q load + in-register RoPE + scale (1/sqrt(Dh) * log2e -> exp2 softmax)
  bf16x8 qf[8];
  #pragma unroll
  for (int dc = 0; dc < 8; ++dc)
    qf[dc] = *(const bf16x8*)(q + (qbase + lq) * D_MODEL + cb + dc*16 + hi*8);
  {
    const float qsc = 0.08838834764831845f * 1.4426950408889634f;
    const int s = qb*256 + w*32 + lq;
    #pragma unroll
    for (int dc = 0; dc < 4; ++dc){
      const int j0 = dc*16 + hi*8;
      const float4 c0 = *(const float4*)(ct + s*64 + j0);
      const float4 c1 = *(const float4*)(ct + s*64 + j0 + 4);
      const float4 s0_ = *(const float4*)(st + s*64 + j0);
      const float4 s1_ = *(const float4*)(st + s*64 + j0 + 4);
      const float cc[8] = {c0.x,c0.y,c0.z,c0.w,c1.x,c1.y,c1.z,c1.w};
      const float ss[8] = {s0_.x,s0_.y,s0_.z,s0_.w,s1_.x,s1_.y,s1_.z,s1_.w};
      #pragma unroll
      for (int e = 0; e < 8; ++e){
        const float x1 = bf2f((unsigned short)qf[dc][e]);
        const float x2 = bf2f((unsigned short)qf[dc + 4][e]);
        qf[dc][e]     = (short)f2bf((x1 * cc[e] - x2 * ss[e]) * qsc);
        qf[dc + 4][e] = (short)f2bf((x2 * cc[e] + x1 * ss[e]) * qsc);
      }
    }
  }

  f32x16 O[4];
  #pragma unroll
  for (int nb = 0; nb < 4; ++nb)
    #pragma unroll
    for (int r = 0; r < 16; ++r) O[nb][r] = 0.0f;
  float m = -1e30f, lsum = 0.0f;

  stageK(0, 0); stageV(0, 0);

  for (int kb = 0; kb < SEQ/64; ++kb){
    const bool more = (kb + 1 < SEQ/64);
    asm volatile("s_waitcnt vmcnt(0)" ::: "memory");
    __builtin_amdgcn_s_barrier();
    __builtin_amdgcn_sched_barrier(0);
    if (more){ stageK((kb + 1) & 1, kb + 1); stageV((kb + 1) & 1, kb + 1); }
    const char* Kb = Ks + (kb & 1)*16384;
    const char* Vb = Vs + (kb & 1)*16384;

    // S^T = K * Q^T (scores in log2 domain)
    f32x16 s0, s1;
    #pragma unroll
    for (int r = 0; r < 16; ++r){ s0[r] = 0.0f; s1[r] = 0.0f; }
    __builtin_amdgcn_s_setprio(1);
    #pragma unroll
    for (int dc = 0; dc < 8; ++dc){
      const int ch = dc*2 + hi;
      const bf16x8 k0 = *(const bf16x8*)(Kb + lq*256 + ((ch ^ (lq & 15)) * 16));
      const bf16x8 k1 = *(const bf16x8*)(Kb + (32 + lq)*256 + ((ch ^ (lq & 15)) * 16));
      s0 = __builtin_amdgcn_mfma_f32_32x32x16_bf16(k0, qf[dc], s0, 0, 0, 0);
      s1 = __builtin_amdgcn_mfma_f32_32x32x16_bf16(k1, qf[dc], s1, 0, 0, 0);
    }
    __builtin_amdgcn_s_setprio(0);

    // online softmax (proven shfl_xor cross-half reductions)
    float mt = s0[0];
    #pragma unroll
    for (int r = 1; r < 16; ++r) mt = fmaxf(mt, s0[r]);
    #pragma unroll
    for (int r = 0; r < 16; ++r) mt = fmaxf(mt, s1[r]);
    mt = fmaxf(mt, __shfl_xor(mt, 32));

    if (!__all(mt <= m + 8.0f)){
      const float mnew = fmaxf(m, mt);
      const float al = __builtin_amdgcn_exp2f(m - mnew);
      m = mnew;
      lsum *= al;
      #pragma unroll
      for (int r = 0; r < 16; ++r){
        const int crow = (r & 3) + 8*(r >> 2) + 4*hi;
        const float albr = __shfl(al, crow);
        #pragma unroll
        for (int nb = 0; nb < 4; ++nb) O[nb][r] *= albr;
      }
    }

    float E[32];
    float sum = 0.0f;
    #pragma unroll
    for (int r = 0; r < 16; ++r){ E[r] = __builtin_amdgcn_exp2f(s0[r] - m); sum += E[r]; }
    #pragma unroll
    for (int r = 0; r < 16; ++r){ E[16 + r] = __builtin_amdgcn_exp2f(s1[r] - m); sum += E[16 + r]; }
    sum += __shfl_xor(sum, 32);
    lsum += sum;

    // repack P (C-layout) -> PV A-fragments (proven R7 shfl_xor + select)
    bf16x8 pa[4];
    #pragma unroll
    for (int c = 0; c < 4; ++c){
      const int rb = c * 8;
      const uint a_ = cvtpk(E[rb + 0], E[rb + 1]);
      const uint b_ = cvtpk(E[rb + 2], E[rb + 3]);
      const uint c_ = cvtpk(E[rb + 4], E[rb + 5]);
      const uint d_ = cvtpk(E[rb + 6], E[rb + 7]);
      const uint sa = (uint)__shfl_xor((int)a_, 32);
      const uint sb = (uint)__shfl_xor((int)b_, 32);
      const uint sc = (uint)__shfl_xor((int)c_, 32);
      const uint sd = (uint)__shfl_xor((int)d_, 32);
      union { uint u[4]; bf16x8 v; } uu;
      uu.u[0] = hi ? sc : a_;
      uu.u[1] = hi ? sd : b_;
      uu.u[2] = hi ? c_ : sa;
      uu.u[3] = hi ? d_ : sb;
      pa[c] = uu.v;
    }

    // O += P * V
    __builtin_amdgcn_s_setprio(1);
    #pragma unroll
    for (int c = 0; c < 4; ++c){
      const int ch = c*2 + hi;
      #pragma unroll
      for (int nb = 0; nb < 4; ++nb){
        const int vr = nb*32 + lq;
        const bf16x8 vf = *(const bf16x8*)(Vb + vr*128 + ((ch ^ (vr & 7)) * 16));
        O[nb] = __builtin_amdgcn_mfma_f32_32x32x16_bf16(pa[c], vf, O[nb], 0, 0, 0);
      }
    }
    __builtin_amdgcn_s_setprio(0);
  }

  const float rinv = 1.0f / lsum;
  #pragma unroll
  for (int r = 0; r < 16; ++r){
    const int crow = (r & 3) + 8*(r >> 2) + 4*hi;
    const float rb_ = __shfl(rinv, crow);
    #pragma unroll
    for (int nb = 0; nb < 4; ++nb)
      o[(qbase + crow) * D_MODEL + cb + nb*32 + lq] = f2bf(O[nb][r] * rb_);
  }
}

// ---------------------------------------------------------------------------
extern "C" void kernel_launch(void* const* d_in, const int* in_sizes, int n_in,
                              void* d_out, int out_size, void* d_ws, size_t ws_size,
                              hipStream_t stream){
  const float* hidden = (const float*)d_in[0];
  const float* Wq = (const float*)d_in[1];
  const float* Wc = (const float*)d_in[2];
  const float* Wk = (const float*)d_in[3];
  const float* Wv = (const float*)d_in[4];
  const float* Wo = (const float*)d_in[5];
  float* out = (float*)d_out;

  char* ws = (char*)d_ws;
  size_t off = 0;
  auto alloc = [&](size_t bytes)->char*{
    char* p = ws + off; off += (bytes + 255) & ~(size_t)255; return p;
  };
  unsigned short* Wqt  = (unsigned short*)alloc((size_t)D_MODEL * D_MODEL * 2);   // 32 MB
  unsigned short* Wct  = (unsigned short*)alloc((size_t)D_LATENT * D_MODEL * 2);  // 4 MB
  unsigned short* Wkvt = (unsigned short*)alloc((size_t)2 * D_MODEL * D_LATENT * 2);
  unsigned short* Wot  = (unsigned short*)alloc((size_t)D_MODEL * D_MODEL * 2);
  unsigned short* latent = (unsigned short*)alloc((size_t)ROWS * D_LATENT * 2);
  unsigned short* qbuf = (unsigned short*)alloc((size_t)ROWS * D_MODEL * 2);
  unsigned short* kbuf = (unsigned short*)alloc((size_t)ROWS * D_MODEL * 2);
  unsigned short* attnb= (unsigned short*)alloc((size_t)ROWS * D_MODEL * 2);
  float* lpart = (float*)alloc((size_t)2 * ROWS * D_LATENT * 4);  // 16 MB
  float* ctab = (float*)alloc((size_t)SEQ * 64 * 4);
  float* stab = (float*)alloc((size_t)SEQ * 64 * 4);
  unsigned short* hbf   = attnb;  // alias: dead until attention writes it
  // Vt [64][128][SEQ] = 33.5MB aliases Wqt (32MB) + first 1.5MB of Wct;
  // both dead by the time the KV GEMM writes.
  unsigned short* vtbuf = Wqt;

  const dim3 B256(256);

  // merged preprocessing: hidden convert + rope tables; all 5 transposes
  prep_kernel<<<8704, B256, 0, stream>>>(hidden, hbf, ctab, stab);
  transpose_all<<<9728, B256, 0, stream>>>(
      Wq, Wqt, Wo, Wot, Wk, Wkvt, Wv, Wkvt + (size_t)D_MODEL*D_LATENT, Wc, Wct);

  // latent projection: split-K x2 (256 blocks) -> f32 partials -> reduce
  gemm_splitk_kernel<<<dim3(D_LATENT/128, ROWS/128, 2), B256, 0, stream>>>(
      hbf, Wct, lpart, ROWS, D_LATENT, D_MODEL, D_MODEL/2);
  latent_reduce<<<(ROWS*(size_t)D_LATENT)/2048, B256, 0, stream>>>(
      lpart, latent, (size_t)ROWS * D_LATENT);

  // Q projection
  gemm256_kernel<false><<<dim3(D_MODEL/256, ROWS/256), dim3(512), 0, stream>>>(
      hbf, Wqt, qbuf, qbuf, 1 << 30, D_MODEL, D_MODEL, ROWS, D_MODEL, D_MODEL, 0);
  // fused K+V projection: N = 8192, split at 4096 -> kbuf / Vt (transposed)
  gemm256_kernel<false><<<dim3(2*D_MODEL/256, ROWS/256), dim3(512), 0, stream>>>(
      latent, Wkvt, kbuf, vtbuf, D_MODEL, D_MODEL, 0, ROWS, 2*D_MODEL, D_LATENT, 1);

  // RoPE on K only (Q-RoPE folded into attn)
  rope_apply<<<(ROWS * NUM_HEADS * 64) / 256, B256, 0, stream>>>(kbuf, ctab, stab, 1.0f);

  // attention
  attn_kernel<<<dim3(BATCH * NUM_HEADS, SEQ/256), dim3(512), 0, stream>>>(
      qbuf, kbuf, vtbuf, ctab, stab, attnb);

  // output projection (f32 out)
  gemm256_kernel<true><<<dim3(D_MODEL/256, ROWS/256), dim3(512), 0, stream>>>(
      attnb, Wot, out, out, 1 << 30, D_MODEL, D_MODEL, ROWS, D_MODEL, D_MODEL, 0);
}

// Round 18
// 566.555 us; speedup vs baseline: 1.0806x; 1.0199x over previous
//
#include <hip/hip_runtime.h>
#include <hip/hip_bf16.h>
#include <cstdint>
#include <cstddef>

#define D_MODEL 4096
#define D_LATENT 512
#define NUM_HEADS 32
#define HEAD_DIM 128
#define BATCH 2
#define SEQ 2048
#define ROWS (BATCH*SEQ)   // 4096

typedef __attribute__((ext_vector_type(8))) short bf16x8;
typedef __attribute__((ext_vector_type(4))) float f32x4;
typedef __attribute__((ext_vector_type(16))) float f32x16;
typedef unsigned int uint;

static __device__ __forceinline__ unsigned short f2bf(float f){
  union { float f; uint32_t u; } v; v.f = f;
  uint32_t r = (v.u + 0x7fffu + ((v.u >> 16) & 1u)) >> 16;
  return (unsigned short)r;
}
static __device__ __forceinline__ float bf2f(unsigned short h){
  union { uint32_t u; float f; } v; v.u = ((uint32_t)h) << 16;
  return v.f;
}
static __device__ __forceinline__ uint cvtpk(float lo, float hi2){
  uint r;
  asm("v_cvt_pk_bf16_f32 %0, %1, %2" : "=v"(r) : "v"(lo), "v"(hi2));
  return r;
}
static __device__ __forceinline__ void gload16(const void* g, void* l){
  __builtin_amdgcn_global_load_lds(
      (const __attribute__((address_space(1))) void*)g,
      (__attribute__((address_space(3))) void*)l, 16, 0, 0);
}

// ---------------------------------------------------------------------------
// prep: blocks [0,8192) convert hidden f32->bf16 (8 elems/thread);
// blocks [8192,8704) fill RoPE cos/sin tables [SEQ][64].
// ---------------------------------------------------------------------------
__global__ __launch_bounds__(256) void prep_kernel(
    const float* __restrict__ in, unsigned short* __restrict__ out,
    float* __restrict__ ct, float* __restrict__ st){
  const int bid = blockIdx.x;
  if (bid < 8192){
    const size_t i = ((size_t)bid * 256 + threadIdx.x) * 8;
    const float4 lo = *(const float4*)(in + i);
    const float4 hi = *(const float4*)(in + i + 4);
    uint4 d; unsigned short* dp = (unsigned short*)&d;
    dp[0]=f2bf(lo.x); dp[1]=f2bf(lo.y); dp[2]=f2bf(lo.z); dp[3]=f2bf(lo.w);
    dp[4]=f2bf(hi.x); dp[5]=f2bf(hi.y); dp[6]=f2bf(hi.z); dp[7]=f2bf(hi.w);
    *(uint4*)(out + i) = d;
  } else {
    const int i = (bid - 8192) * 256 + threadIdx.x;
    if (i >= SEQ * 64) return;
    const int s = i >> 6, j = i & 63;
    const float inv = powf(10000.0f, -(float)j / 64.0f);
    const double a = (double)s * (double)inv;
    ct[i] = (float)cos(a);
    st[i] = (float)sin(a);
  }
}

// ---------------------------------------------------------------------------
// Weight transposes. [K][N] f32 -> [N][K] bf16, 64x64 tiles.
// Wk gets a RoPE-pair permutation on its output rows: orig head-col d ->
// sigma(d) = ((d&63)>>4)*32 + (d>>6)*16 + (d&15), so in the 256x256 GEMM
// epilogue each lane's fragments n=2q/2q+1 hold the RoPE pair (d, d+64),
// d = (wc&1)*32 + q*16 + lr. Inverse applied at the epilogue write.
// ---------------------------------------------------------------------------
static __device__ __forceinline__ void tr_tile(
    const float* __restrict__ W, unsigned short* __restrict__ Wt,
    int K, int N, int k0, int n0){
  __shared__ float tile[64][65];
  const int t = threadIdx.x;
  #pragma unroll
  for (int j = 0; j < 16; ++j){
    const int idx = t + 256*j;
    const int r = idx >> 6, c = idx & 63;
    tile[r][c] = W[(size_t)(k0 + r) * N + n0 + c];
  }
  __syncthreads();
  #pragma unroll
  for (int j = 0; j < 16; ++j){
    const int idx = t + 256*j;
    const int r = idx >> 6, c = idx & 63;
    Wt[(size_t)(n0 + r) * K + k0 + c] = f2bf(tile[c][r]);
  }
}

static __device__ __forceinline__ void tr_tile_krope(
    const float* __restrict__ W, unsigned short* __restrict__ Wt,
    int K, int N, int k0, int n0){
  __shared__ float tile[64][65];
  const int t = threadIdx.x;
  #pragma unroll
  for (int j = 0; j < 16; ++j){
    const int idx = t + 256*j;
    const int r = idx >> 6, c = idx & 63;
    tile[r][c] = W[(size_t)(k0 + r) * N + n0 + c];
  }
  __syncthreads();
  #pragma unroll
  for (int j = 0; j < 16; ++j){
    const int idx = t + 256*j;
    const int r = idx >> 6, c = idx & 63;
    const int n = n0 + r;
    const int h = n >> 7, d = n & 127;
    const int g = ((d & 63) >> 4)*32 + (d >> 6)*16 + (d & 15);
    Wt[(size_t)(h*128 + g) * K + k0 + c] = f2bf(tile[c][r]);
  }
}

__global__ __launch_bounds__(256) void transpose_all(
    const float* __restrict__ Wq, unsigned short* __restrict__ Wqt,
    const float* __restrict__ Wo, unsigned short* __restrict__ Wot,
    const float* __restrict__ Wk, unsigned short* __restrict__ Wkt,
    const float* __restrict__ Wv, unsigned short* __restrict__ Wvt,
    const float* __restrict__ Wc, unsigned short* __restrict__ Wct){
  const int b = blockIdx.x;
  if (b < 4096){                       // Wq: K=4096, N=4096
    tr_tile(Wq, Wqt, D_MODEL, D_MODEL, (b & 63) * 64, (b >> 6) * 64);
  } else if (b < 8192){                // Wo
    const int l = b - 4096;
    tr_tile(Wo, Wot, D_MODEL, D_MODEL, (l & 63) * 64, (l >> 6) * 64);
  } else if (b < 8704){                // Wk: K=512, N=4096 (RoPE-permuted)
    const int l = b - 8192;
    tr_tile_krope(Wk, Wkt, D_LATENT, D_MODEL, (l & 7) * 64, (l >> 3) * 64);
  } else if (b < 9216){                // Wv
    const int l = b - 8704;
    tr_tile(Wv, Wvt, D_LATENT, D_MODEL, (l & 7) * 64, (l >> 3) * 64);
  } else {                             // Wc: K=4096, N=512
    const int l = b - 9216;
    tr_tile(Wc, Wct, D_MODEL, D_LATENT, (l & 63) * 64, (l >> 6) * 64);
  }
}

// ---------------------------------------------------------------------------
// 128x128 split-K GEMM for the latent projection: blockIdx.z = K-half,
// writes f32 partials to Cpart[z]. XCD-swizzled grid (per z-slice).
// ---------------------------------------------------------------------------
__global__ __launch_bounds__(256) void gemm_splitk_kernel(
    const unsigned short* __restrict__ A, const unsigned short* __restrict__ Bt,
    float* __restrict__ Cpart, int M, int N, int Kfull, int Kpart){
  __shared__ __align__(16) char As[128 * 128];
  __shared__ __align__(16) char Bs[128 * 128];
  const int t = threadIdx.x;
  const int kz = blockIdx.z;
  const int nbx = gridDim.x;
  const int nwg = nbx * gridDim.y;
  int bid = blockIdx.y * nbx + blockIdx.x;
  bid = (bid & 7) * (nwg >> 3) + (bid >> 3);
  const int m0 = (bid / nbx) * 128, n0 = (bid % nbx) * 128;
  const int l = t & 63, wid = t >> 6;
  const int wr = wid >> 1, wcn = wid & 1;
  const int lr = l & 15, lg = l >> 4;

  const int srow = l >> 3;
  const int gch  = (l & 7) ^ srow;
  const size_t kofs = (size_t)kz * Kpart;
  const unsigned short* gA = A  + (size_t)(m0 + wid*32 + srow) * Kfull + kofs + gch*8;
  const unsigned short* gB = Bt + (size_t)(n0 + wid*32 + srow) * Kfull + kofs + gch*8;
  char* lA = As + wid*4096;
  char* lB = Bs + wid*4096;

  f32x4 acc[4][4];
  #pragma unroll
  for (int i = 0; i < 4; ++i)
    #pragma unroll
    for (int j = 0; j < 4; ++j)
      #pragma unroll
      for (int r = 0; r < 4; ++r) acc[i][j][r] = 0.0f;

  const int kTiles = Kpart >> 6;
  for (int kt = 0; kt < kTiles; ++kt){
    const size_t ko = (size_t)kt << 6;
    #pragma unroll
    for (int i = 0; i < 4; ++i){
      gload16(gA + (size_t)i*8*Kfull + ko, lA + i*1024);
      gload16(gB + (size_t)i*8*Kfull + ko, lB + i*1024);
    }
    __syncthreads();
    #pragma unroll
    for (int kc = 0; kc < 2; ++kc){
      bf16x8 af[4], bfv[4];
      const int ch = kc*4 + lg;
      #pragma unroll
      for (int mb = 0; mb < 4; ++mb){
        const int row = wr*64 + mb*16 + lr;
        af[mb] = *(const bf16x8*)(As + row*128 + ((ch ^ (row & 7)) * 16));
      }
      #pragma unroll
      for (int nb = 0; nb < 4; ++nb){
        const int row = wcn*64 + nb*16 + lr;
        bfv[nb] = *(const bf16x8*)(Bs + row*128 + ((ch ^ (row & 7)) * 16));
      }
      #pragma unroll
      for (int mb = 0; mb < 4; ++mb)
        #pragma unroll
        for (int nb = 0; nb < 4; ++nb)
          acc[mb][nb] = __builtin_amdgcn_mfma_f32_16x16x32_bf16(af[mb], bfv[nb], acc[mb][nb], 0, 0, 0);
    }
    __syncthreads();
  }
  float* Cp = Cpart + (size_t)kz * M * N;
  #pragma unroll
  for (int mb = 0; mb < 4; ++mb)
    #pragma unroll
    for (int nb = 0; nb < 4; ++nb)
      #pragma unroll
      for (int r = 0; r < 4; ++r){
        const int row = m0 + wr*64 + mb*16 + lg*4 + r;
        const int col = n0 + wcn*64 + nb*16 + lr;
        Cp[(size_t)row * N + col] = acc[mb][nb][r];
      }
}

// ---------------------------------------------------------------------------
// latent partial reduce: bf16 out = f2bf(p0 + p1), 8 elems/thread.
// ---------------------------------------------------------------------------
__global__ __launch_bounds__(256) void latent_reduce(
    const float* __restrict__ p, unsigned short* __restrict__ out, size_t n){
  const size_t i = ((size_t)blockIdx.x * 256 + threadIdx.x) * 8;
  const float4 a0 = *(const float4*)(p + i);
  const float4 a1 = *(const float4*)(p + i + 4);
  const float4 b0 = *(const float4*)(p + n + i);
  const float4 b1 = *(const float4*)(p + n + i + 4);
  uint4 d; unsigned short* dp = (unsigned short*)&d;
  dp[0]=f2bf(a0.x+b0.x); dp[1]=f2bf(a0.y+b0.y); dp[2]=f2bf(a0.z+b0.z); dp[3]=f2bf(a0.w+b0.w);
  dp[4]=f2bf(a1.x+b1.x); dp[5]=f2bf(a1.y+b1.y); dp[6]=f2bf(a1.z+b1.z); dp[7]=f2bf(a1.w+b1.w);
  *(uint4*)(out + i) = d;
}

// ---------------------------------------------------------------------------
// 256x256 8-phase GEMM (T2+T3+T4+T5) + T1 XCD swizzle. vt_mode=1 epilogues:
// K half (n0 < nsplit): in-register RoPE (pre-permuted Wk rows), standard
// layout out to Cp. V half: Vt [B*H][128][SEQ] transposed scatter to Cp2.
// ---------------------------------------------------------------------------
template<int MH>
static __device__ __forceinline__ void rdAh(bf16x8 (&a_)[4][2], const char* buf,
                                            int wr, int lr, int lg){
  #pragma unroll
  for (int mm = 0; mm < 4; ++mm)
    #pragma unroll
    for (int kc = 0; kc < 2; ++kc){
      const int row = wr*128 + (MH*4 + mm)*16 + lr;
      const int ch = kc*4 + lg;
      a_[mm][kc] = *(const bf16x8*)(buf + row*128 + ((ch ^ (row & 7)) * 16));
    }
}
template<int NH>
static __device__ __forceinline__ void rdBh(bf16x8 (&b_)[2][2][2], const char* buf,
                                            int wc, int lr, int lg){
  #pragma unroll
  for (int nn = 0; nn < 2; ++nn)
    #pragma unroll
    for (int kc = 0; kc < 2; ++kc){
      const int row = wc*64 + (NH*2 + nn)*16 + lr;
      const int ch = kc*4 + lg;
      b_[NH][nn][kc] = *(const bf16x8*)(buf + row*128 + ((ch ^ (row & 7)) * 16));
    }
}
template<int MH, int NH>
static __device__ __forceinline__ void mfq(f32x4 (&acc)[8][4],
    const bf16x8 (&a_)[4][2], const bf16x8 (&b_)[2][2][2]){
  __builtin_amdgcn_s_setprio(1);
  #pragma unroll
  for (int kc = 0; kc < 2; ++kc)
    #pragma unroll
    for (int mm = 0; mm < 4; ++mm)
      #pragma unroll
      for (int nn = 0; nn < 2; ++nn)
        acc[MH*4+mm][NH*2+nn] = __builtin_amdgcn_mfma_f32_16x16x32_bf16(
            a_[mm][kc], b_[NH][nn][kc], acc[MH*4+mm][NH*2+nn], 0, 0, 0);
  __builtin_amdgcn_s_setprio(0);
}

#define G256_BAR  __builtin_amdgcn_s_barrier()
#define G256_LGK0 do{ asm volatile("s_waitcnt lgkmcnt(0)" ::: "memory"); \
                      __builtin_amdgcn_sched_barrier(0); }while(0)
#define G256_VM(n) asm volatile("s_waitcnt vmcnt(" #n ")" ::: "memory")

template<bool OF32>
__global__ __launch_bounds__(512, 2) void gemm256_kernel(
    const unsigned short* __restrict__ A, const unsigned short* __restrict__ Bt,
    void* __restrict__ Cp, void* __restrict__ Cp2, int nsplit, int ldc, int ldc2,
    int M, int N, int K, int vt_mode,
    const float* __restrict__ ct, const float* __restrict__ st){
  __shared__ __align__(16) char lds[131072];
  char* const As0 = lds;
  char* const As1 = lds + 32768;
  char* const Bs0 = lds + 65536;
  char* const Bs1 = lds + 98304;

  const int t = threadIdx.x;
  const int l = t & 63, wid = t >> 6;
  const int wr = wid >> 2, wc = wid & 3;
  const int lr = l & 15, lg = l >> 4;
  const int nbx = gridDim.x;
  const int nwg = nbx * gridDim.y;
  int bid = blockIdx.y * nbx + blockIdx.x;
  bid = (bid & 7) * (nwg >> 3) + (bid >> 3);
  const int m0 = (bid / nbx) * 256, n0 = (bid % nbx) * 256;

  const int srow = t >> 3;
  const int pch = t & 7;
  const int gch = pch ^ (srow & 7);
  const unsigned short* gAb = A  + (size_t)(m0 + srow) * K + gch*8;
  const unsigned short* gBb = Bt + (size_t)(n0 + srow) * K + gch*8;
  const int ldso = srow*128 + pch*16;

  auto stA = [&](char* dst, int half, int kcol){
    const unsigned short* g = gAb + (size_t)half*128*K + kcol;
    gload16(g,                dst + half*16384 + ldso);
    gload16(g + (size_t)64*K, dst + half*16384 + 8192 + ldso);
  };
  auto stB = [&](char* dst, int half, int kcol){
    const unsigned short* g = gBb + (size_t)half*128*K + kcol;
    gload16(g,                dst + half*16384 + ldso);
    gload16(g + (size_t)64*K, dst + half*16384 + 8192 + ldso);
  };

  f32x4 acc[8][4];
  #pragma unroll
  for (int m = 0; m < 8; ++m)
    #pragma unroll
    for (int n = 0; n < 4; ++n)
      #pragma unroll
      for (int r = 0; r < 4; ++r) acc[m][n][r] = 0.0f;
  bf16x8 a_[4][2];
  bf16x8 b_[2][2][2];

  const int niter = K >> 7;
  stA(As0, 0, 0); stA(As0, 1, 0); stB(Bs0, 0, 0); stB(Bs0, 1, 0);
  stA(As1, 0, 64);
  G256_VM(2);
  G256_BAR;
  __builtin_amdgcn_sched_barrier(0);

  for (int j = 0; j < niter; ++j){
    const int k0 = j << 7;
    const bool more = (j + 1 < niter);
    rdAh<0>(a_, As0, wr, lr, lg);
    rdBh<0>(b_, Bs0, wc, lr, lg);
    stA(As1, 1, k0 + 64);
    G256_BAR; G256_LGK0;
    mfq<0,0>(acc, a_, b_);
    G256_BAR;
    rdBh<1>(b_, Bs0, wc, lr, lg);
    stB(Bs1, 0, k0 + 64);
    G256_BAR; G256_LGK0;
    mfq<0,1>(acc, a_, b_);
    G256_BAR;
    rdAh<1>(a_, As0, wr, lr, lg);
    stB(Bs1, 1, k0 + 64);
    G256_BAR; G256_LGK0;
    mfq<1,0>(acc, a_, b_);
    G256_BAR;
    if (more){ stA(As0, 0, k0 + 128); G256_VM(2); }
    else     { G256_VM(0); }
    G256_BAR;
    __builtin_amdgcn_sched_barrier(0);
    mfq<1,1>(acc, a_, b_);
    G256_BAR;
    rdAh<0>(a_, As1, wr, lr, lg);
    rdBh<0>(b_, Bs1, wc, lr, lg);
    if (more) stA(As0, 1, k0 + 128);
    G256_BAR; G256_LGK0;
    mfq<0,0>(acc, a_, b_);
    G256_BAR;
    rdBh<1>(b_, Bs1, wc, lr, lg);
    if (more) stB(Bs0, 0, k0 + 128);
    G256_BAR; G256_LGK0;
    mfq<0,1>(acc, a_, b_);
    G256_BAR;
    rdAh<1>(a_, As1, wr, lr, lg);
    if (more) stB(Bs0, 1, k0 + 128);
    G256_BAR; G256_LGK0;
    mfq<1,0>(acc, a_, b_);
    G256_BAR;
    if (more){ stA(As1, 0, k0 + 192); G256_VM(2); }
    G256_BAR;
    __builtin_amdgcn_sched_barrier(0);
    mfq<1,1>(acc, a_, b_);
    G256_BAR;
  }

  if (vt_mode){
    if (n0 < nsplit){
      // K half: in-register RoPE. Lane fragment n=2q holds orig d =
      // (wc&1)*32 + q*16 + lr, n=2q+1 holds d+64 (Wk rows pre-permuted).
      unsigned short* kp = (unsigned short*)Cp;
      const int hbase = (n0 + wc*64) >> 7;
      #pragma unroll
      for (int m = 0; m < 8; ++m)
        #pragma unroll
        for (int r = 0; r < 4; ++r){
          const int row = m0 + wr*128 + m*16 + lg*4 + r;
          const int s = row & (SEQ - 1);
          #pragma unroll
          for (int q = 0; q < 2; ++q){
            const int d = (wc & 1)*32 + q*16 + lr;
            const float c  = ct[s*64 + d];
            const float sn = st[s*64 + d];
            const float x1 = acc[m][2*q][r];
            const float x2 = acc[m][2*q + 1][r];
            kp[(size_t)row * ldc + hbase*128 + d]      = f2bf(x1*c - x2*sn);
            kp[(size_t)row * ldc + hbase*128 + d + 64] = f2bf(x2*c + x1*sn);
          }
        }
      return;
    }
    // V half: write transposed -> vt[(b*32+h)*128 + d][s]
    unsigned short* vtp = (unsigned short*)Cp2;
    #pragma unroll
    for (int m = 0; m < 8; ++m)
      #pragma unroll
      for (int n = 0; n < 4; ++n)
        #pragma unroll
        for (int r = 0; r < 4; ++r){
          const int row = m0 + wr*128 + m*16 + lg*4 + r;   // b*SEQ + s
          const int col = (n0 - nsplit) + wc*64 + n*16 + lr; // h*128 + d
          const size_t didx = ((size_t)(((row >> 11) << 5) | (col >> 7)) * 128
                               + (col & 127)) * SEQ + (row & (SEQ - 1));
          vtp[didx] = f2bf(acc[m][n][r]);
        }
    return;
  }
  void* outp = Cp;
  int c0 = n0, ld = ldc;
  if (n0 >= nsplit){ outp = Cp2; c0 = n0 - nsplit; ld = ldc2; }
  #pragma unroll
  for (int m = 0; m < 8; ++m)
    #pragma unroll
    for (int n = 0; n < 4; ++n)
      #pragma unroll
      for (int r = 0; r < 4; ++r){
        const int row = m0 + wr*128 + m*16 + lg*4 + r;
        const int col = c0 + wc*64 + n*16 + lr;
        if constexpr (OF32) ((float*)outp)[(size_t)row * ld + col] = acc[m][n][r];
        else ((unsigned short*)outp)[(size_t)row * ld + col] = f2bf(acc[m][n][r]);
      }
}

// ---------------------------------------------------------------------------
// Flash attention, 8 waves x 32 q-rows, KVBLK=64, 32x32x16 MFMA.
// Proven R10 body, byte-identical to R15/R17.
// ---------------------------------------------------------------------------
__global__ __launch_bounds__(512) void attn_kernel(
    const unsigned short* __restrict__ q, const unsigned short* __restrict__ kp,
    const unsigned short* __restrict__ vt, const float* __restrict__ ct,
    const float* __restrict__ st, unsigned short* __restrict__ o){
  __shared__ __align__(16) char Ks[2 * 16384];
  __shared__ __align__(16) char Vs[2 * 16384];
  const int t = threadIdx.x;
  const int l = t & 63, w = t >> 6;
  const int lq = l & 31, hi = l >> 5;
  const int bh = blockIdx.x, qb = blockIdx.y;   // bh-major: qb shares XCD
  const int b = bh >> 5;
  const size_t qbase = (size_t)b * SEQ + qb*256 + w*32;
  const size_t cb = (size_t)(bh & 31) * 128;

  auto stageK = [&](int buf, int kb){
    const size_t kr0 = (size_t)b * SEQ + (size_t)kb*64;
    char* kdst = Ks + buf*16384 + w*2048;
    #pragma unroll
    for (int i = 0; i < 2; ++i){
      const int r = w*8 + i*4 + (l >> 4);
      const int g = (l & 15) ^ (r & 15);
      gload16(kp + (kr0 + r) * D_MODEL + cb + g*8, kdst + i*1024);
    }
  };
  auto stageV = [&](int buf, int kb){
    char* vdst = Vs + buf*16384 + w*2048;
    #pragma unroll
    for (int i = 0; i < 2; ++i){
      const int r = w*16 + i*8 + (l >> 3);
      const int g = (l & 7) ^ (r & 7);
      gload16(vt + ((size_t)bh*128 + r) * SEQ + (size_t)kb*64 + g*8, vdst + i*1024);
    }
  };

  // Q load + in-register RoPE + scale (1/sqrt(Dh) * log2e -> exp2 softmax)
  bf16x8 qf[8];
  #pragma unroll
  for (int dc = 0; dc < 8; ++dc)
    qf[dc] = *(const bf16x8*)(q + (qbase + lq) * D_MODEL + cb + dc*16 + hi*8);
  {
    const float qsc = 0.08838834764831845f * 1.4426950408889634f;
    const int s = qb*256 + w*32 + lq;
    #pragma unroll
    for (int dc = 0; dc < 4; ++dc){
      const int j0 = dc*16 + hi*8;
      const float4 c0 = *(const float4*)(ct + s*64 + j0);
      const float4 c1 = *(const float4*)(ct + s*64 + j0 + 4);
      const float4 s0_ = *(const float4*)(st + s*64 + j0);
      const float4 s1_ = *(const float4*)(st + s*64 + j0 + 4);
      const float cc[8] = {c0.x,c0.y,c0.z,c0.w,c1.x,c1.y,c1.z,c1.w};
      const float ss[8] = {s0_.x,s0_.y,s0_.z,s0_.w,s1_.x,s1_.y,s1_.z,s1_.w};
      #pragma unroll
      for (int e = 0; e < 8; ++e){
        const float x1 = bf2f((unsigned short)qf[dc][e]);
        const float x2 = bf2f((unsigned short)qf[dc + 4][e]);
        qf[dc][e]     = (short)f2bf((x1 * cc[e] - x2 * ss[e]) * qsc);
        qf[dc + 4][e] = (short)f2bf((x2 * cc[e] + x1 * ss[e]) * qsc);
      }
    }
  }

  f32x16 O[4];
  #pragma unroll
  for (int nb = 0; nb < 4; ++nb)
    #pragma unroll
    for (int r = 0; r < 16; ++r) O[nb][r] = 0.0f;
  float m = -1e30f, lsum = 0.0f;

  stageK(0, 0); stageV(0, 0);

  for (int kb = 0; kb < SEQ/64; ++kb){
    const bool more = (kb + 1 < SEQ/64);
    asm volatile("s_waitcnt vmcnt(0)" ::: "memory");
    __builtin_amdgcn_s_barrier();
    __builtin_amdgcn_sched_barrier(0);
    if (more){ stageK((kb + 1) & 1, kb + 1); stageV((kb + 1) & 1, kb + 1); }
    const char* Kb = Ks + (kb & 1)*16384;
    const char* Vb = Vs + (kb & 1)*16384;

    // S^T = K * Q^T (scores in log2 domain)
    f32x16 s0, s1;
    #pragma unroll
    for (int r = 0; r < 16; ++r){ s0[r] = 0.0f; s1[r] = 0.0f; }
    __builtin_amdgcn_s_setprio(1);
    #pragma unroll
    for (int dc = 0; dc < 8; ++dc){
      const int ch = dc*2 + hi;
      const bf16x8 k0 = *(const bf16x8*)(Kb + lq*256 + ((ch ^ (lq & 15)) * 16));
      const bf16x8 k1 = *(const bf16x8*)(Kb + (32 + lq)*256 + ((ch ^ (lq & 15)) * 16));
      s0 = __builtin_amdgcn_mfma_f32_32x32x16_bf16(k0, qf[dc], s0, 0, 0, 0);
      s1 = __builtin_amdgcn_mfma_f32_32x32x16_bf16(k1, qf[dc], s1, 0, 0, 0);
    }
    __builtin_amdgcn_s_setprio(0);

    // online softmax (proven shfl_xor cross-half reductions)
    float mt = s0[0];
    #pragma unroll
    for (int r = 1; r < 16; ++r) mt = fmaxf(mt, s0[r]);
    #pragma unroll
    for (int r = 0; r < 16; ++r) mt = fmaxf(mt, s1[r]);
    mt = fmaxf(mt, __shfl_xor(mt, 32));

    if (!__all(mt <= m + 8.0f)){
      const float mnew = fmaxf(m, mt);
      const float al = __builtin_amdgcn_exp2f(m - mnew);
      m = mnew;
      lsum *= al;
      #pragma unroll
      for (int r = 0; r < 16; ++r){
        const int crow = (r & 3) + 8*(r >> 2) + 4*hi;
        const float albr = __shfl(al, crow);
        #pragma unroll
        for (int nb = 0; nb < 4; ++nb) O[nb][r] *= albr;
      }
    }

    float E[32];
    float sum = 0.0f;
    #pragma unroll
    for (int r = 0; r < 16; ++r){ E[r] = __builtin_amdgcn_exp2f(s0[r] - m); sum += E[r]; }
    #pragma unroll
    for (int r = 0; r < 16; ++r){ E[16 + r] = __builtin_amdgcn_exp2f(s1[r] - m); sum += E[16 + r]; }
    sum += __shfl_xor(sum, 32);
    lsum += sum;

    // repack P (C-layout) -> PV A-fragments (proven R7 shfl_xor + select)
    bf16x8 pa[4];
    #pragma unroll
    for (int c = 0; c < 4; ++c){
      const int rb = c * 8;
      const uint a_ = cvtpk(E[rb + 0], E[rb + 1]);
      const uint b_ = cvtpk(E[rb + 2], E[rb + 3]);
      const uint c_ = cvtpk(E[rb + 4], E[rb + 5]);
      const uint d_ = cvtpk(E[rb + 6], E[rb + 7]);
      const uint sa = (uint)__shfl_xor((int)a_, 32);
      const uint sb = (uint)__shfl_xor((int)b_, 32);
      const uint sc = (uint)__shfl_xor((int)c_, 32);
      const uint sd = (uint)__shfl_xor((int)d_, 32);
      union { uint u[4]; bf16x8 v; } uu;
      uu.u[0] = hi ? sc : a_;
      uu.u[1] = hi ? sd : b_;
      uu.u[2] = hi ? c_ : sa;
      uu.u[3] = hi ? d_ : sb;
      pa[c] = uu.v;
    }

    // O += P * V
    __builtin_amdgcn_s_setprio(1);
    #pragma unroll
    for (int c = 0; c < 4; ++c){
      const int ch = c*2 + hi;
      #pragma unroll
      for (int nb = 0; nb < 4; ++nb){
        const int vr = nb*32 + lq;
        const bf16x8 vf = *(const bf16x8*)(Vb + vr*128 + ((ch ^ (vr & 7)) * 16));
        O[nb] = __builtin_amdgcn_mfma_f32_32x32x16_bf16(pa[c], vf, O[nb], 0, 0, 0);
      }
    }
    __builtin_amdgcn_s_setprio(0);
  }

  const float rinv = 1.0f / lsum;
  #pragma unroll
  for (int r = 0; r < 16; ++r){
    const int crow = (r & 3) + 8*(r >> 2) + 4*hi;
    const float rb_ = __shfl(rinv, crow);
    #pragma unroll
    for (int nb = 0; nb < 4; ++nb)
      o[(qbase + crow) * D_MODEL + cb + nb*32 + lq] = f2bf(O[nb][r] * rb_);
  }
}

// ---------------------------------------------------------------------------
extern "C" void kernel_launch(void* const* d_in, const int* in_sizes, int n_in,
                              void* d_out, int out_size, void* d_ws, size_t ws_size,
                              hipStream_t stream){
  const float* hidden = (const float*)d_in[0];
  const float* Wq = (const float*)d_in[1];
  const float* Wc = (const float*)d_in[2];
  const float* Wk = (const float*)d_in[3];
  const float* Wv = (const float*)d_in[4];
  const float* Wo = (const float*)d_in[5];
  float* out = (float*)d_out;

  char* ws = (char*)d_ws;
  size_t off = 0;
  auto alloc = [&](size_t bytes)->char*{
    char* p = ws + off; off += (bytes + 255) & ~(size_t)255; return p;
  };
  unsigned short* Wqt  = (unsigned short*)alloc((size_t)D_MODEL * D_MODEL * 2);   // 32 MB
  unsigned short* Wct  = (unsigned short*)alloc((size_t)D_LATENT * D_MODEL * 2);  // 4 MB
  unsigned short* Wkvt = (unsigned short*)alloc((size_t)2 * D_MODEL * D_LATENT * 2);
  unsigned short* Wot  = (unsigned short*)alloc((size_t)D_MODEL * D_MODEL * 2);
  unsigned short* latent = (unsigned short*)alloc((size_t)ROWS * D_LATENT * 2);
  unsigned short* qbuf = (unsigned short*)alloc((size_t)ROWS * D_MODEL * 2);
  unsigned short* kbuf = (unsigned short*)alloc((size_t)ROWS * D_MODEL * 2);
  unsigned short* attnb= (unsigned short*)alloc((size_t)ROWS * D_MODEL * 2);
  float* lpart = (float*)alloc((size_t)2 * ROWS * D_LATENT * 4);  // 16 MB
  float* ctab = (float*)alloc((size_t)SEQ * 64 * 4);
  float* stab = (float*)alloc((size_t)SEQ * 64 * 4);
  unsigned short* hbf   = attnb;  // alias: dead until attention writes it
  // Vt [64][128][SEQ] = 33.5MB aliases Wqt (32MB) + first 1.5MB of Wct;
  // both dead by the time the KV GEMM writes.
  unsigned short* vtbuf = Wqt;

  const dim3 B256(256);

  // merged preprocessing: hidden convert + rope tables; all 5 transposes
  prep_kernel<<<8704, B256, 0, stream>>>(hidden, hbf, ctab, stab);
  transpose_all<<<9728, B256, 0, stream>>>(
      Wq, Wqt, Wo, Wot, Wk, Wkvt, Wv, Wkvt + (size_t)D_MODEL*D_LATENT, Wc, Wct);

  // latent projection: split-K x2 (256 blocks) -> f32 partials -> reduce
  gemm_splitk_kernel<<<dim3(D_LATENT/128, ROWS/128, 2), B256, 0, stream>>>(
      hbf, Wct, lpart, ROWS, D_LATENT, D_MODEL, D_MODEL/2);
  latent_reduce<<<(ROWS*(size_t)D_LATENT)/2048, B256, 0, stream>>>(
      lpart, latent, (size_t)ROWS * D_LATENT);

  // Q projection
  gemm256_kernel<false><<<dim3(D_MODEL/256, ROWS/256), dim3(512), 0, stream>>>(
      hbf, Wqt, qbuf, qbuf, 1 << 30, D_MODEL, D_MODEL, ROWS, D_MODEL, D_MODEL, 0,
      nullptr, nullptr);
  // fused K+V projection: N = 8192, split at 4096.
  // K half: RoPE fused in epilogue -> kbuf. V half: transposed -> Vt.
  gemm256_kernel<false><<<dim3(2*D_MODEL/256, ROWS/256), dim3(512), 0, stream>>>(
      latent, Wkvt, kbuf, vtbuf, D_MODEL, D_MODEL, 0, ROWS, 2*D_MODEL, D_LATENT, 1,
      ctab, stab);

  // attention (Q-RoPE folded in-kernel; K-RoPE folded in KV epilogue)
  attn_kernel<<<dim3(BATCH * NUM_HEADS, SEQ/256), dim3(512), 0, stream>>>(
      qbuf, kbuf, vtbuf, ctab, stab, attnb);

  // output projection (f32 out)
  gemm256_kernel<true><<<dim3(D_MODEL/256, ROWS/256), dim3(512), 0, stream>>>(
      attnb, Wot, out, out, 1 << 30, D_MODEL, D_MODEL, ROWS, D_MODEL, D_MODEL, 0,
      nullptr, nullptr);
}

// Round 19
// 562.120 us; speedup vs baseline: 1.0892x; 1.0079x over previous
//
#include <hip/hip_runtime.h>
#include <hip/hip_bf16.h>
#include <cstdint>
#include <cstddef>

#define D_MODEL 4096
#define D_LATENT 512
#define NUM_HEADS 32
#define HEAD_DIM 128
#define BATCH 2
#define SEQ 2048
#define ROWS (BATCH*SEQ)   // 4096

typedef __attribute__((ext_vector_type(8))) short bf16x8;
typedef __attribute__((ext_vector_type(4))) float f32x4;
typedef __attribute__((ext_vector_type(16))) float f32x16;
typedef unsigned int uint;

static __device__ __forceinline__ unsigned short f2bf(float f){
  union { float f; uint32_t u; } v; v.f = f;
  uint32_t r = (v.u + 0x7fffu + ((v.u >> 16) & 1u)) >> 16;
  return (unsigned short)r;
}
static __device__ __forceinline__ float bf2f(unsigned short h){
  union { uint32_t u; float f; } v; v.u = ((uint32_t)h) << 16;
  return v.f;
}
static __device__ __forceinline__ uint cvtpk(float lo, float hi2){
  uint r;
  asm("v_cvt_pk_bf16_f32 %0, %1, %2" : "=v"(r) : "v"(lo), "v"(hi2));
  return r;
}
static __device__ __forceinline__ void gload16(const void* g, void* l){
  __builtin_amdgcn_global_load_lds(
      (const __attribute__((address_space(1))) void*)g,
      (__attribute__((address_space(3))) void*)l, 16, 0, 0);
}

// ---------------------------------------------------------------------------
// Weight transpose tile helpers. [K][N] f32 -> [N][K] bf16, 64x64 tiles.
// tr_tile_krope additionally applies the RoPE-pair row permutation
// sigma(d) = ((d&63)>>4)*32 + (d>>6)*16 + (d&15) for the fused-K-RoPE
// epilogue in the 256x256 GEMM.
// ---------------------------------------------------------------------------
static __device__ __forceinline__ void tr_tile(
    const float* __restrict__ W, unsigned short* __restrict__ Wt,
    int K, int N, int k0, int n0){
  __shared__ float tile[64][65];
  const int t = threadIdx.x;
  #pragma unroll
  for (int j = 0; j < 16; ++j){
    const int idx = t + 256*j;
    const int r = idx >> 6, c = idx & 63;
    tile[r][c] = W[(size_t)(k0 + r) * N + n0 + c];
  }
  __syncthreads();
  #pragma unroll
  for (int j = 0; j < 16; ++j){
    const int idx = t + 256*j;
    const int r = idx >> 6, c = idx & 63;
    Wt[(size_t)(n0 + r) * K + k0 + c] = f2bf(tile[c][r]);
  }
}

static __device__ __forceinline__ void tr_tile_krope(
    const float* __restrict__ W, unsigned short* __restrict__ Wt,
    int K, int N, int k0, int n0){
  __shared__ float tile[64][65];
  const int t = threadIdx.x;
  #pragma unroll
  for (int j = 0; j < 16; ++j){
    const int idx = t + 256*j;
    const int r = idx >> 6, c = idx & 63;
    tile[r][c] = W[(size_t)(k0 + r) * N + n0 + c];
  }
  __syncthreads();
  #pragma unroll
  for (int j = 0; j < 16; ++j){
    const int idx = t + 256*j;
    const int r = idx >> 6, c = idx & 63;
    const int n = n0 + r;
    const int h = n >> 7, d = n & 127;
    const int g = ((d & 63) >> 4)*32 + (d >> 6)*16 + (d & 15);
    Wt[(size_t)(h*128 + g) * K + k0 + c] = f2bf(tile[c][r]);
  }
}

// ---------------------------------------------------------------------------
// setup: ALL preprocessing in one launch. Flat block ranges:
//   [0,8192)        hidden f32->bf16 (8 elems/thread)
//   [8192,8704)     RoPE cos/sin tables [SEQ][64]
//   [8704,12800)    Wq transpose
//   [12800,16896)   Wo transpose
//   [16896,17408)   Wk transpose (RoPE-permuted)
//   [17408,17920)   Wv transpose
//   [17920,18432)   Wc transpose
// ---------------------------------------------------------------------------
__global__ __launch_bounds__(256) void setup_kernel(
    const float* __restrict__ in, unsigned short* __restrict__ out,
    float* __restrict__ ct, float* __restrict__ st,
    const float* __restrict__ Wq, unsigned short* __restrict__ Wqt,
    const float* __restrict__ Wo, unsigned short* __restrict__ Wot,
    const float* __restrict__ Wk, unsigned short* __restrict__ Wkt,
    const float* __restrict__ Wv, unsigned short* __restrict__ Wvt,
    const float* __restrict__ Wc, unsigned short* __restrict__ Wct){
  const int b = blockIdx.x;
  if (b < 8192){
    const size_t i = ((size_t)b * 256 + threadIdx.x) * 8;
    const float4 lo = *(const float4*)(in + i);
    const float4 hi = *(const float4*)(in + i + 4);
    uint4 d; unsigned short* dp = (unsigned short*)&d;
    dp[0]=f2bf(lo.x); dp[1]=f2bf(lo.y); dp[2]=f2bf(lo.z); dp[3]=f2bf(lo.w);
    dp[4]=f2bf(hi.x); dp[5]=f2bf(hi.y); dp[6]=f2bf(hi.z); dp[7]=f2bf(hi.w);
    *(uint4*)(out + i) = d;
  } else if (b < 8704){
    const int i = (b - 8192) * 256 + threadIdx.x;
    if (i >= SEQ * 64) return;
    const int s = i >> 6, j = i & 63;
    const float inv = powf(10000.0f, -(float)j / 64.0f);
    const double a = (double)s * (double)inv;
    ct[i] = (float)cos(a);
    st[i] = (float)sin(a);
  } else if (b < 12800){               // Wq: K=4096, N=4096
    const int l = b - 8704;
    tr_tile(Wq, Wqt, D_MODEL, D_MODEL, (l & 63) * 64, (l >> 6) * 64);
  } else if (b < 16896){               // Wo
    const int l = b - 12800;
    tr_tile(Wo, Wot, D_MODEL, D_MODEL, (l & 63) * 64, (l >> 6) * 64);
  } else if (b < 17408){               // Wk: K=512, N=4096 (RoPE-permuted)
    const int l = b - 16896;
    tr_tile_krope(Wk, Wkt, D_LATENT, D_MODEL, (l & 7) * 64, (l >> 3) * 64);
  } else if (b < 17920){               // Wv
    const int l = b - 17408;
    tr_tile(Wv, Wvt, D_LATENT, D_MODEL, (l & 7) * 64, (l >> 3) * 64);
  } else {                             // Wc: K=4096, N=512
    const int l = b - 17920;
    tr_tile(Wc, Wct, D_MODEL, D_LATENT, (l & 63) * 64, (l >> 6) * 64);
  }
}

// ---------------------------------------------------------------------------
// 128x128 split-K GEMM for the latent projection: blockIdx.z = K-half,
// writes f32 partials to Cpart[z]. XCD-swizzled grid (per z-slice).
// ---------------------------------------------------------------------------
__global__ __launch_bounds__(256) void gemm_splitk_kernel(
    const unsigned short* __restrict__ A, const unsigned short* __restrict__ Bt,
    float* __restrict__ Cpart, int M, int N, int Kfull, int Kpart){
  __shared__ __align__(16) char As[128 * 128];
  __shared__ __align__(16) char Bs[128 * 128];
  const int t = threadIdx.x;
  const int kz = blockIdx.z;
  const int nbx = gridDim.x;
  const int nwg = nbx * gridDim.y;
  int bid = blockIdx.y * nbx + blockIdx.x;
  bid = (bid & 7) * (nwg >> 3) + (bid >> 3);
  const int m0 = (bid / nbx) * 128, n0 = (bid % nbx) * 128;
  const int l = t & 63, wid = t >> 6;
  const int wr = wid >> 1, wcn = wid & 1;
  const int lr = l & 15, lg = l >> 4;

  const int srow = l >> 3;
  const int gch  = (l & 7) ^ srow;
  const size_t kofs = (size_t)kz * Kpart;
  const unsigned short* gA = A  + (size_t)(m0 + wid*32 + srow) * Kfull + kofs + gch*8;
  const unsigned short* gB = Bt + (size_t)(n0 + wid*32 + srow) * Kfull + kofs + gch*8;
  char* lA = As + wid*4096;
  char* lB = Bs + wid*4096;

  f32x4 acc[4][4];
  #pragma unroll
  for (int i = 0; i < 4; ++i)
    #pragma unroll
    for (int j = 0; j < 4; ++j)
      #pragma unroll
      for (int r = 0; r < 4; ++r) acc[i][j][r] = 0.0f;

  const int kTiles = Kpart >> 6;
  for (int kt = 0; kt < kTiles; ++kt){
    const size_t ko = (size_t)kt << 6;
    #pragma unroll
    for (int i = 0; i < 4; ++i){
      gload16(gA + (size_t)i*8*Kfull + ko, lA + i*1024);
      gload16(gB + (size_t)i*8*Kfull + ko, lB + i*1024);
    }
    __syncthreads();
    #pragma unroll
    for (int kc = 0; kc < 2; ++kc){
      bf16x8 af[4], bfv[4];
      const int ch = kc*4 + lg;
      #pragma unroll
      for (int mb = 0; mb < 4; ++mb){
        const int row = wr*64 + mb*16 + lr;
        af[mb] = *(const bf16x8*)(As + row*128 + ((ch ^ (row & 7)) * 16));
      }
      #pragma unroll
      for (int nb = 0; nb < 4; ++nb){
        const int row = wcn*64 + nb*16 + lr;
        bfv[nb] = *(const bf16x8*)(Bs + row*128 + ((ch ^ (row & 7)) * 16));
      }
      #pragma unroll
      for (int mb = 0; mb < 4; ++mb)
        #pragma unroll
        for (int nb = 0; nb < 4; ++nb)
          acc[mb][nb] = __builtin_amdgcn_mfma_f32_16x16x32_bf16(af[mb], bfv[nb], acc[mb][nb], 0, 0, 0);
    }
    __syncthreads();
  }
  float* Cp = Cpart + (size_t)kz * M * N;
  #pragma unroll
  for (int mb = 0; mb < 4; ++mb)
    #pragma unroll
    for (int nb = 0; nb < 4; ++nb)
      #pragma unroll
      for (int r = 0; r < 4; ++r){
        const int row = m0 + wr*64 + mb*16 + lg*4 + r;
        const int col = n0 + wcn*64 + nb*16 + lr;
        Cp[(size_t)row * N + col] = acc[mb][nb][r];
      }
}

// ---------------------------------------------------------------------------
// latent partial reduce: bf16 out = f2bf(p0 + p1), 8 elems/thread.
// ---------------------------------------------------------------------------
__global__ __launch_bounds__(256) void latent_reduce(
    const float* __restrict__ p, unsigned short* __restrict__ out, size_t n){
  const size_t i = ((size_t)blockIdx.x * 256 + threadIdx.x) * 8;
  const float4 a0 = *(const float4*)(p + i);
  const float4 a1 = *(const float4*)(p + i + 4);
  const float4 b0 = *(const float4*)(p + n + i);
  const float4 b1 = *(const float4*)(p + n + i + 4);
  uint4 d; unsigned short* dp = (unsigned short*)&d;
  dp[0]=f2bf(a0.x+b0.x); dp[1]=f2bf(a0.y+b0.y); dp[2]=f2bf(a0.z+b0.z); dp[3]=f2bf(a0.w+b0.w);
  dp[4]=f2bf(a1.x+b1.x); dp[5]=f2bf(a1.y+b1.y); dp[6]=f2bf(a1.z+b1.z); dp[7]=f2bf(a1.w+b1.w);
  *(uint4*)(out + i) = d;
}

// ---------------------------------------------------------------------------
// 256x256 8-phase GEMM (T2+T3+T4+T5) + T1 XCD swizzle. vt_mode=1 epilogues:
// K half (n0 < nsplit): in-register RoPE (pre-permuted Wk rows), standard
// layout out to Cp. V half: Vt [B*H][128][SEQ] transposed scatter to Cp2.
// ---------------------------------------------------------------------------
template<int MH>
static __device__ __forceinline__ void rdAh(bf16x8 (&a_)[4][2], const char* buf,
                                            int wr, int lr, int lg){
  #pragma unroll
  for (int mm = 0; mm < 4; ++mm)
    #pragma unroll
    for (int kc = 0; kc < 2; ++kc){
      const int row = wr*128 + (MH*4 + mm)*16 + lr;
      const int ch = kc*4 + lg;
      a_[mm][kc] = *(const bf16x8*)(buf + row*128 + ((ch ^ (row & 7)) * 16));
    }
}
template<int NH>
static __device__ __forceinline__ void rdBh(bf16x8 (&b_)[2][2][2], const char* buf,
                                            int wc, int lr, int lg){
  #pragma unroll
  for (int nn = 0; nn < 2; ++nn)
    #pragma unroll
    for (int kc = 0; kc < 2; ++kc){
      const int row = wc*64 + (NH*2 + nn)*16 + lr;
      const int ch = kc*4 + lg;
      b_[NH][nn][kc] = *(const bf16x8*)(buf + row*128 + ((ch ^ (row & 7)) * 16));
    }
}
template<int MH, int NH>
static __device__ __forceinline__ void mfq(f32x4 (&acc)[8][4],
    const bf16x8 (&a_)[4][2], const bf16x8 (&b_)[2][2][2]){
  __builtin_amdgcn_s_setprio(1);
  #pragma unroll
  for (int kc = 0; kc < 2; ++kc)
    #pragma unroll
    for (int mm = 0; mm < 4; ++mm)
      #pragma unroll
      for (int nn = 0; nn < 2; ++nn)
        acc[MH*4+mm][NH*2+nn] = __builtin_amdgcn_mfma_f32_16x16x32_bf16(
            a_[mm][kc], b_[NH][nn][kc], acc[MH*4+mm][NH*2+nn], 0, 0, 0);
  __builtin_amdgcn_s_setprio(0);
}

#define G256_BAR  __builtin_amdgcn_s_barrier()
#define G256_LGK0 do{ asm volatile("s_waitcnt lgkmcnt(0)" ::: "memory"); \
                      __builtin_amdgcn_sched_barrier(0); }while(0)
#define G256_VM(n) asm volatile("s_waitcnt vmcnt(" #n ")" ::: "memory")

template<bool OF32>
__global__ __launch_bounds__(512, 2) void gemm256_kernel(
    const unsigned short* __restrict__ A, const unsigned short* __restrict__ Bt,
    void* __restrict__ Cp, void* __restrict__ Cp2, int nsplit, int ldc, int ldc2,
    int M, int N, int K, int vt_mode,
    const float* __restrict__ ct, const float* __restrict__ st){
  __shared__ __align__(16) char lds[131072];
  char* const As0 = lds;
  char* const As1 = lds + 32768;
  char* const Bs0 = lds + 65536;
  char* const Bs1 = lds + 98304;

  const int t = threadIdx.x;
  const int l = t & 63, wid = t >> 6;
  const int wr = wid >> 2, wc = wid & 3;
  const int lr = l & 15, lg = l >> 4;
  const int nbx = gridDim.x;
  const int nwg = nbx * gridDim.y;
  int bid = blockIdx.y * nbx + blockIdx.x;
  bid = (bid & 7) * (nwg >> 3) + (bid >> 3);
  const int m0 = (bid / nbx) * 256, n0 = (bid % nbx) * 256;

  const int srow = t >> 3;
  const int pch = t & 7;
  const int gch = pch ^ (srow & 7);
  const unsigned short* gAb = A  + (size_t)(m0 + srow) * K + gch*8;
  const unsigned short* gBb = Bt + (size_t)(n0 + srow) * K + gch*8;
  const int ldso = srow*128 + pch*16;

  auto stA = [&](char* dst, int half, int kcol){
    const unsigned short* g = gAb + (size_t)half*128*K + kcol;
    gload16(g,                dst + half*16384 + ldso);
    gload16(g + (size_t)64*K, dst + half*16384 + 8192 + ldso);
  };
  auto stB = [&](char* dst, int half, int kcol){
    const unsigned short* g = gBb + (size_t)half*128*K + kcol;
    gload16(g,                dst + half*16384 + ldso);
    gload16(g + (size_t)64*K, dst + half*16384 + 8192 + ldso);
  };

  f32x4 acc[8][4];
  #pragma unroll
  for (int m = 0; m < 8; ++m)
    #pragma unroll
    for (int n = 0; n < 4; ++n)
      #pragma unroll
      for (int r = 0; r < 4; ++r) acc[m][n][r] = 0.0f;
  bf16x8 a_[4][2];
  bf16x8 b_[2][2][2];

  const int niter = K >> 7;
  stA(As0, 0, 0); stA(As0, 1, 0); stB(Bs0, 0, 0); stB(Bs0, 1, 0);
  stA(As1, 0, 64);
  G256_VM(2);
  G256_BAR;
  __builtin_amdgcn_sched_barrier(0);

  for (int j = 0; j < niter; ++j){
    const int k0 = j << 7;
    const bool more = (j + 1 < niter);
    rdAh<0>(a_, As0, wr, lr, lg);
    rdBh<0>(b_, Bs0, wc, lr, lg);
    stA(As1, 1, k0 + 64);
    G256_BAR; G256_LGK0;
    mfq<0,0>(acc, a_, b_);
    G256_BAR;
    rdBh<1>(b_, Bs0, wc, lr, lg);
    stB(Bs1, 0, k0 + 64);
    G256_BAR; G256_LGK0;
    mfq<0,1>(acc, a_, b_);
    G256_BAR;
    rdAh<1>(a_, As0, wr, lr, lg);
    stB(Bs1, 1, k0 + 64);
    G256_BAR; G256_LGK0;
    mfq<1,0>(acc, a_, b_);
    G256_BAR;
    if (more){ stA(As0, 0, k0 + 128); G256_VM(2); }
    else     { G256_VM(0); }
    G256_BAR;
    __builtin_amdgcn_sched_barrier(0);
    mfq<1,1>(acc, a_, b_);
    G256_BAR;
    rdAh<0>(a_, As1, wr, lr, lg);
    rdBh<0>(b_, Bs1, wc, lr, lg);
    if (more) stA(As0, 1, k0 + 128);
    G256_BAR; G256_LGK0;
    mfq<0,0>(acc, a_, b_);
    G256_BAR;
    rdBh<1>(b_, Bs1, wc, lr, lg);
    if (more) stB(Bs0, 0, k0 + 128);
    G256_BAR; G256_LGK0;
    mfq<0,1>(acc, a_, b_);
    G256_BAR;
    rdAh<1>(a_, As1, wr, lr, lg);
    if (more) stB(Bs0, 1, k0 + 128);
    G256_BAR; G256_LGK0;
    mfq<1,0>(acc, a_, b_);
    G256_BAR;
    if (more){ stA(As1, 0, k0 + 192); G256_VM(2); }
    G256_BAR;
    __builtin_amdgcn_sched_barrier(0);
    mfq<1,1>(acc, a_, b_);
    G256_BAR;
  }

  if (vt_mode){
    if (n0 < nsplit){
      // K half: in-register RoPE. Lane fragment n=2q holds orig d =
      // (wc&1)*32 + q*16 + lr, n=2q+1 holds d+64 (Wk rows pre-permuted).
      unsigned short* kp = (unsigned short*)Cp;
      const int hbase = (n0 + wc*64) >> 7;
      #pragma unroll
      for (int m = 0; m < 8; ++m)
        #pragma unroll
        for (int r = 0; r < 4; ++r){
          const int row = m0 + wr*128 + m*16 + lg*4 + r;
          const int s = row & (SEQ - 1);
          #pragma unroll
          for (int q = 0; q < 2; ++q){
            const int d = (wc & 1)*32 + q*16 + lr;
            const float c  = ct[s*64 + d];
            const float sn = st[s*64 + d];
            const float x1 = acc[m][2*q][r];
            const float x2 = acc[m][2*q + 1][r];
            kp[(size_t)row * ldc + hbase*128 + d]      = f2bf(x1*c - x2*sn);
            kp[(size_t)row * ldc + hbase*128 + d + 64] = f2bf(x2*c + x1*sn);
          }
        }
      return;
    }
    // V half: write transposed -> vt[(b*32+h)*128 + d][s]
    unsigned short* vtp = (unsigned short*)Cp2;
    #pragma unroll
    for (int m = 0; m < 8; ++m)
      #pragma unroll
      for (int n = 0; n < 4; ++n)
        #pragma unroll
        for (int r = 0; r < 4; ++r){
          const int row = m0 + wr*128 + m*16 + lg*4 + r;   // b*SEQ + s
          const int col = (n0 - nsplit) + wc*64 + n*16 + lr; // h*128 + d
          const size_t didx = ((size_t)(((row >> 11) << 5) | (col >> 7)) * 128
                               + (col & 127)) * SEQ + (row & (SEQ - 1));
          vtp[didx] = f2bf(acc[m][n][r]);
        }
    return;
  }
  void* outp = Cp;
  int c0 = n0, ld = ldc;
  if (n0 >= nsplit){ outp = Cp2; c0 = n0 - nsplit; ld = ldc2; }
  #pragma unroll
  for (int m = 0; m < 8; ++m)
    #pragma unroll
    for (int n = 0; n < 4; ++n)
      #pragma unroll
      for (int r = 0; r < 4; ++r){
        const int row = m0 + wr*128 + m*16 + lg*4 + r;
        const int col = c0 + wc*64 + n*16 + lr;
        if constexpr (OF32) ((float*)outp)[(size_t)row * ld + col] = acc[m][n][r];
        else ((unsigned short*)outp)[(size_t)row * ld + col] = f2bf(acc[m][n][r]);
      }
}

// ---------------------------------------------------------------------------
// Flash attention, 8 waves x 32 q-rows, KVBLK=64, 32x32x16 MFMA.
// Proven R10 body, byte-identical to R15/R17/R18.
// ---------------------------------------------------------------------------
__global__ __launch_bounds__(512) void attn_kernel(
    const unsigned short* __restrict__ q, const unsigned short* __restrict__ kp,
    const unsigned short* __restrict__ vt, const float* __restrict__ ct,
    const float* __restrict__ st, unsigned short* __restrict__ o){
  __shared__ __align__(16) char Ks[2 * 16384];
  __shared__ __align__(16) char Vs[2 * 16384];
  const int t = threadIdx.x;
  const int l = t & 63, w = t >> 6;
  const int lq = l & 31, hi = l >> 5;
  const int bh = blockIdx.x, qb = blockIdx.y;   // bh-major: qb shares XCD
  const int b = bh >> 5;
  const size_t qbase = (size_t)b * SEQ + qb*256 + w*32;
  const size_t cb = (size_t)(bh & 31) * 128;

  auto stageK = [&](int buf, int kb){
    const size_t kr0 = (size_t)b * SEQ + (size_t)kb*64;
    char* kdst = Ks + buf*16384 + w*2048;
    #pragma unroll
    for (int i = 0; i < 2; ++i){
      const int r = w*8 + i*4 + (l >> 4);
      const int g = (l & 15) ^ (r & 15);
      gload16(kp + (kr0 + r) * D_MODEL + cb + g*8, kdst + i*1024);
    }
  };
  auto stageV = [&](int buf, int kb){
    char* vdst = Vs + buf*16384 + w*2048;
    #pragma unroll
    for (int i = 0; i < 2; ++i){
      const int r = w*16 + i*8 + (l >> 3);
      const int g = (l & 7) ^ (r & 7);
      gload16(vt + ((size_t)bh*128 + r) * SEQ + (size_t)kb*64 + g*8, vdst + i*1024);
    }
  };

  // Q load + in-register RoPE + scale (1/sqrt(Dh) * log2e -> exp2 softmax)
  bf16x8 qf[8];
  #pragma unroll
  for (int dc = 0; dc < 8; ++dc)
    qf[dc] = *(const bf16x8*)(q + (qbase + lq) * D_MODEL + cb + dc*16 + hi*8);
  {
    const float qsc = 0.08838834764831845f * 1.4426950408889634f;
    const int s = qb*256 + w*32 + lq;
    #pragma unroll
    for (int dc = 0; dc < 4; ++dc){
      const int j0 = dc*16 + hi*8;
      const float4 c0 = *(const float4*)(ct + s*64 + j0);
      const float4 c1 = *(const float4*)(ct + s*64 + j0 + 4);
      const float4 s0_ = *(const float4*)(st + s*64 + j0);
      const float4 s1_ = *(const float4*)(st + s*64 + j0 + 4);
      const float cc[8] = {c0.x,c0.y,c0.z,c0.w,c1.x,c1.y,c1.z,c1.w};
      const float ss[8] = {s0_.x,s0_.y,s0_.z,s0_.w,s1_.x,s1_.y,s1_.z,s1_.w};
      #pragma unroll
      for (int e = 0; e < 8; ++e){
        const float x1 = bf2f((unsigned short)qf[dc][e]);
        const float x2 = bf2f((unsigned short)qf[dc + 4][e]);
        qf[dc][e]     = (short)f2bf((x1 * cc[e] - x2 * ss[e]) * qsc);
        qf[dc + 4][e] = (short)f2bf((x2 * cc[e] + x1 * ss[e]) * qsc);
      }
    }
  }

  f32x16 O[4];
  #pragma unroll
  for (int nb = 0; nb < 4; ++nb)
    #pragma unroll
    for (int r = 0; r < 16; ++r) O[nb][r] = 0.0f;
  float m = -1e30f, lsum = 0.0f;

  stageK(0, 0); stageV(0, 0);

  for (int kb = 0; kb < SEQ/64; ++kb){
    const bool more = (kb + 1 < SEQ/64);
    asm volatile("s_waitcnt vmcnt(0)" ::: "memory");
    __builtin_amdgcn_s_barrier();
    __builtin_amdgcn_sched_barrier(0);
    if (more){ stageK((kb + 1) & 1, kb + 1); stageV((kb + 1) & 1, kb + 1); }
    const char* Kb = Ks + (kb & 1)*16384;
    const char* Vb = Vs + (kb & 1)*16384;

    // S^T = K * Q^T (scores in log2 domain)
    f32x16 s0, s1;
    #pragma unroll
    for (int r = 0; r < 16; ++r){ s0[r] = 0.0f; s1[r] = 0.0f; }
    __builtin_amdgcn_s_setprio(1);
    #pragma unroll
    for (int dc = 0; dc < 8; ++dc){
      const int ch = dc*2 + hi;
      const bf16x8 k0 = *(const bf16x8*)(Kb + lq*256 + ((ch ^ (lq & 15)) * 16));
      const bf16x8 k1 = *(const bf16x8*)(Kb + (32 + lq)*256 + ((ch ^ (lq & 15)) * 16));
      s0 = __builtin_amdgcn_mfma_f32_32x32x16_bf16(k0, qf[dc], s0, 0, 0, 0);
      s1 = __builtin_amdgcn_mfma_f32_32x32x16_bf16(k1, qf[dc], s1, 0, 0, 0);
    }
    __builtin_amdgcn_s_setprio(0);

    // online softmax (proven shfl_xor cross-half reductions)
    float mt = s0[0];
    #pragma unroll
    for (int r = 1; r < 16; ++r) mt = fmaxf(mt, s0[r]);
    #pragma unroll
    for (int r = 0; r < 16; ++r) mt = fmaxf(mt, s1[r]);
    mt = fmaxf(mt, __shfl_xor(mt, 32));

    if (!__all(mt <= m + 8.0f)){
      const float mnew = fmaxf(m, mt);
      const float al = __builtin_amdgcn_exp2f(m - mnew);
      m = mnew;
      lsum *= al;
      #pragma unroll
      for (int r = 0; r < 16; ++r){
        const int crow = (r & 3) + 8*(r >> 2) + 4*hi;
        const float albr = __shfl(al, crow);
        #pragma unroll
        for (int nb = 0; nb < 4; ++nb) O[nb][r] *= albr;
      }
    }

    float E[32];
    float sum = 0.0f;
    #pragma unroll
    for (int r = 0; r < 16; ++r){ E[r] = __builtin_amdgcn_exp2f(s0[r] - m); sum += E[r]; }
    #pragma unroll
    for (int r = 0; r < 16; ++r){ E[16 + r] = __builtin_amdgcn_exp2f(s1[r] - m); sum += E[16 + r]; }
    sum += __shfl_xor(sum, 32);
    lsum += sum;

    // repack P (C-layout) -> PV A-fragments (proven R7 shfl_xor + select)
    bf16x8 pa[4];
    #pragma unroll
    for (int c = 0; c < 4; ++c){
      const int rb = c * 8;
      const uint a_ = cvtpk(E[rb + 0], E[rb + 1]);
      const uint b_ = cvtpk(E[rb + 2], E[rb + 3]);
      const uint c_ = cvtpk(E[rb + 4], E[rb + 5]);
      const uint d_ = cvtpk(E[rb + 6], E[rb + 7]);
      const uint sa = (uint)__shfl_xor((int)a_, 32);
      const uint sb = (uint)__shfl_xor((int)b_, 32);
      const uint sc = (uint)__shfl_xor((int)c_, 32);
      const uint sd = (uint)__shfl_xor((int)d_, 32);
      union { uint u[4]; bf16x8 v; } uu;
      uu.u[0] = hi ? sc : a_;
      uu.u[1] = hi ? sd : b_;
      uu.u[2] = hi ? c_ : sa;
      uu.u[3] = hi ? d_ : sb;
      pa[c] = uu.v;
    }

    // O += P * V
    __builtin_amdgcn_s_setprio(1);
    #pragma unroll
    for (int c = 0; c < 4; ++c){
      const int ch = c*2 + hi;
      #pragma unroll
      for (int nb = 0; nb < 4; ++nb){
        const int vr = nb*32 + lq;
        const bf16x8 vf = *(const bf16x8*)(Vb + vr*128 + ((ch ^ (vr & 7)) * 16));
        O[nb] = __builtin_amdgcn_mfma_f32_32x32x16_bf16(pa[c], vf, O[nb], 0, 0, 0);
      }
    }
    __builtin_amdgcn_s_setprio(0);
  }

  const float rinv = 1.0f / lsum;
  #pragma unroll
  for (int r = 0; r < 16; ++r){
    const int crow = (r & 3) + 8*(r >> 2) + 4*hi;
    const float rb_ = __shfl(rinv, crow);
    #pragma unroll
    for (int nb = 0; nb < 4; ++nb)
      o[(qbase + crow) * D_MODEL + cb + nb*32 + lq] = f2bf(O[nb][r] * rb_);
  }
}

// ---------------------------------------------------------------------------
extern "C" void kernel_launch(void* const* d_in, const int* in_sizes, int n_in,
                              void* d_out, int out_size, void* d_ws, size_t ws_size,
                              hipStream_t stream){
  const float* hidden = (const float*)d_in[0];
  const float* Wq = (const float*)d_in[1];
  const float* Wc = (const float*)d_in[2];
  const float* Wk = (const float*)d_in[3];
  const float* Wv = (const float*)d_in[4];
  const float* Wo = (const float*)d_in[5];
  float* out = (float*)d_out;

  char* ws = (char*)d_ws;
  size_t off = 0;
  auto alloc = [&](size_t bytes)->char*{
    char* p = ws + off; off += (bytes + 255) & ~(size_t)255; return p;
  };
  unsigned short* Wqt  = (unsigned short*)alloc((size_t)D_MODEL * D_MODEL * 2);   // 32 MB
  unsigned short* Wct  = (unsigned short*)alloc((size_t)D_LATENT * D_MODEL * 2);  // 4 MB
  unsigned short* Wkvt = (unsigned short*)alloc((size_t)2 * D_MODEL * D_LATENT * 2);
  unsigned short* Wot  = (unsigned short*)alloc((size_t)D_MODEL * D_MODEL * 2);
  unsigned short* latent = (unsigned short*)alloc((size_t)ROWS * D_LATENT * 2);
  unsigned short* qbuf = (unsigned short*)alloc((size_t)ROWS * D_MODEL * 2);
  unsigned short* kbuf = (unsigned short*)alloc((size_t)ROWS * D_MODEL * 2);
  unsigned short* attnb= (unsigned short*)alloc((size_t)ROWS * D_MODEL * 2);
  float* lpart = (float*)alloc((size_t)2 * ROWS * D_LATENT * 4);  // 16 MB
  float* ctab = (float*)alloc((size_t)SEQ * 64 * 4);
  float* stab = (float*)alloc((size_t)SEQ * 64 * 4);
  unsigned short* hbf   = attnb;  // alias: dead until attention writes it
  // Vt [64][128][SEQ] = 33.5MB aliases Wqt (32MB) + first 1.5MB of Wct;
  // both dead by the time the KV GEMM writes.
  unsigned short* vtbuf = Wqt;

  const dim3 B256(256);

  // ALL preprocessing in one launch (convert + rope tables + 5 transposes)
  setup_kernel<<<18432, B256, 0, stream>>>(
      hidden, hbf, ctab, stab,
      Wq, Wqt, Wo, Wot, Wk, Wkvt, Wv, Wkvt + (size_t)D_MODEL*D_LATENT, Wc, Wct);

  // latent projection: split-K x2 (256 blocks) -> f32 partials -> reduce
  gemm_splitk_kernel<<<dim3(D_LATENT/128, ROWS/128, 2), B256, 0, stream>>>(
      hbf, Wct, lpart, ROWS, D_LATENT, D_MODEL, D_MODEL/2);
  latent_reduce<<<(ROWS*(size_t)D_LATENT)/2048, B256, 0, stream>>>(
      lpart, latent, (size_t)ROWS * D_LATENT);

  // Q projection
  gemm256_kernel<false><<<dim3(D_MODEL/256, ROWS/256), dim3(512), 0, stream>>>(
      hbf, Wqt, qbuf, qbuf, 1 << 30, D_MODEL, D_MODEL, ROWS, D_MODEL, D_MODEL, 0,
      nullptr, nullptr);
  // fused K+V projection: N = 8192, split at 4096.
  // K half: RoPE fused in epilogue -> kbuf. V half: transposed -> Vt.
  gemm256_kernel<false><<<dim3(2*D_MODEL/256, ROWS/256), dim3(512), 0, stream>>>(
      latent, Wkvt, kbuf, vtbuf, D_MODEL, D_MODEL, 0, ROWS, 2*D_MODEL, D_LATENT, 1,
      ctab, stab);

  // attention (Q-RoPE folded in-kernel; K-RoPE folded in KV epilogue)
  attn_kernel<<<dim3(BATCH * NUM_HEADS, SEQ/256), dim3(512), 0, stream>>>(
      qbuf, kbuf, vtbuf, ctab, stab, attnb);

  // output projection (f32 out)
  gemm256_kernel<true><<<dim3(D_MODEL/256, ROWS/256), dim3(512), 0, stream>>>(
      attnb, Wot, out, out, 1 << 30, D_MODEL, D_MODEL, ROWS, D_MODEL, D_MODEL, 0,
      nullptr, nullptr);
}